// Round 1
// baseline (9465.938 us; speedup 1.0000x reference)
//
#include <hip/hip_runtime.h>

#define DIM 200
#define NENT 100000
#define NEDGE 1000000
#define NB 1024
#define NFILT 200
#define FLATSZ 39200

#define NDF ((size_t)NENT * DIM)      /* 20,000,000 floats per node matrix */
#define REGF ((size_t)20100000)       /* region stride: 2*REGF >= NB*FLATSZ */

__device__ __forceinline__ void gAtomicAdd(float* p, float v) { unsafeAtomicAdd(p, v); }
__device__ __forceinline__ void gAtomicAdd(double* p, double v) { unsafeAtomicAdd(p, v); }

// ---------------------------------------------------------------- scatter
// agg[dst] += enorm * x[src] * r[etype]  for edges [e0, e1)
__global__ __launch_bounds__(256) void scatter_edges(
    const float* __restrict__ x, const float* __restrict__ r,
    const float* __restrict__ enorm, const int* __restrict__ src,
    const int* __restrict__ dst, const int* __restrict__ etype,
    float* __restrict__ agg, int e0, int e1)
{
    int e = e0 + blockIdx.x * 4 + (threadIdx.x >> 6);
    int lane = threadIdx.x & 63;
    if (e >= e1) return;
    int s = src[e], d = dst[e], t = etype[e];
    float en = enorm[e];
    if (lane < 50) {
        const float4* xs = (const float4*)(x + (size_t)s * DIM);
        const float4* rs = (const float4*)(r + (size_t)t * DIM);
        float4 xv = xs[lane], rv = rs[lane];
        float* ad = agg + (size_t)d * DIM + lane * 4;
        gAtomicAdd(ad + 0, xv.x * rv.x * en);
        gAtomicAdd(ad + 1, xv.y * rv.y * en);
        gAtomicAdd(ad + 2, xv.z * rv.z * en);
        gAtomicAdd(ad + 3, xv.w * rv.w * en);
    }
}

// ---------------------------------------------------------------- GEMM  C[M,200] (+)= alpha * A[M,K] * B[K,200]
// optional per-column scale on A; optional atomic epilogue (for split-K via blockIdx.y)
__global__ __launch_bounds__(256) void gemm_n200(
    const float* __restrict__ A, long lda, const float* __restrict__ Bw,
    float* __restrict__ C, int M, int K, int chunkK, float alpha,
    const float* __restrict__ colscale, int use_atomic)
{
    __shared__ float As[128][17];
    __shared__ float Bs[16][200];
    int t = threadIdx.x;
    int row0 = blockIdx.x * 128;
    int r = t & 63;
    int cg = t >> 6;            // 4 col groups of 50
    float acc0[50], acc1[50];
#pragma unroll
    for (int c = 0; c < 50; ++c) { acc0[c] = 0.f; acc1[c] = 0.f; }
    int kbegin = blockIdx.y * chunkK;
    int kend = min(kbegin + chunkK, K);
    for (int k0 = kbegin; k0 < kend; k0 += 16) {
        for (int i = t; i < 128 * 16; i += 256) {
            int rr = i >> 4, kk = i & 15;
            int gr = row0 + rr, gk = k0 + kk;
            float v = 0.f;
            if (gr < M && gk < kend) {
                v = A[(size_t)gr * lda + gk];
                if (colscale) v *= colscale[gk];
            }
            As[rr][kk] = v;
        }
        for (int i = t; i < 16 * 200; i += 256) {
            int kk = i / 200, cc = i - kk * 200;
            int gk = k0 + kk;
            Bs[kk][cc] = (gk < kend) ? Bw[(size_t)gk * 200 + cc] : 0.f;
        }
        __syncthreads();
        for (int kk = 0; kk < 16; ++kk) {
            float a0 = As[r][kk], a1 = As[r + 64][kk];
            const float* bp = &Bs[kk][cg * 50];
#pragma unroll
            for (int c = 0; c < 50; ++c) {
                float bv = bp[c];
                acc0[c] = fmaf(a0, bv, acc0[c]);
                acc1[c] = fmaf(a1, bv, acc1[c]);
            }
        }
        __syncthreads();
    }
    int gr0 = row0 + r, gr1 = row0 + r + 64;
    if (gr0 < M) {
        float* cp = C + (size_t)gr0 * 200 + cg * 50;
        if (use_atomic) { for (int c = 0; c < 50; ++c) gAtomicAdd(&cp[c], alpha * acc0[c]); }
        else            { for (int c = 0; c < 50; ++c) cp[c] += alpha * acc0[c]; }
    }
    if (gr1 < M) {
        float* cp = C + (size_t)gr1 * 200 + cg * 50;
        if (use_atomic) { for (int c = 0; c < 50; ++c) gAtomicAdd(&cp[c], alpha * acc1[c]); }
        else            { for (int c = 0; c < 50; ++c) cp[c] += alpha * acc1[c]; }
    }
}

// ---------------------------------------------------------------- per-column stats (200 cols)
__global__ __launch_bounds__(256) void colstats(
    const float* __restrict__ X, int M, int rpb,
    double* __restrict__ s1, double* __restrict__ s2)
{
    int c = threadIdx.x;
    if (c >= 200) return;
    int r0 = blockIdx.x * rpb;
    int r1 = min(r0 + rpb, M);
    float sum = 0.f, sq = 0.f;
    for (int rr = r0; rr < r1; ++rr) {
        float v = X[(size_t)rr * 200 + c];
        sum += v; sq += v * v;
    }
    gAtomicAdd(&s1[c], (double)sum);
    gAtomicAdd(&s2[c], (double)sq);
}

__global__ void finalize_stats(const double* __restrict__ s1, const double* __restrict__ s2,
                               const float* __restrict__ g, const float* __restrict__ bb,
                               float* __restrict__ sc, float* __restrict__ sh,
                               int ncols, double count)
{
    int c = threadIdx.x;
    if (c >= ncols) return;
    double m = s1[c] / count;
    double v = s2[c] / count - m * m;
    double scd = (double)g[c] / sqrt(v + 1e-5);
    sc[c] = (float)scd;
    sh[c] = (float)((double)bb[c] - m * scd);
}

// act: 0 = tanh, 1 = relu ; X is [M,200] row-major, n4 = M*50 float4s
__global__ __launch_bounds__(256) void bn_act_200(
    float* __restrict__ X, const float* __restrict__ sc, const float* __restrict__ sh,
    long n4, int act)
{
    long stride = (long)gridDim.x * blockDim.x;
    for (long i = (long)blockIdx.x * blockDim.x + threadIdx.x; i < n4; i += stride) {
        int c4 = (int)(i % 50) * 4;
        float4 v = ((const float4*)X)[i];
        float a0 = v.x * sc[c4 + 0] + sh[c4 + 0];
        float a1 = v.y * sc[c4 + 1] + sh[c4 + 1];
        float a2 = v.z * sc[c4 + 2] + sh[c4 + 2];
        float a3 = v.w * sc[c4 + 3] + sh[c4 + 3];
        if (act == 0) { a0 = tanhf(a0); a1 = tanhf(a1); a2 = tanhf(a2); a3 = tanhf(a3); }
        else { a0 = fmaxf(a0, 0.f); a1 = fmaxf(a1, 0.f); a2 = fmaxf(a2, 0.f); a3 = fmaxf(a3, 0.f); }
        ((float4*)X)[i] = make_float4(a0, a1, a2, a3);
    }
}

__global__ __launch_bounds__(256) void init_bias200(
    float* __restrict__ C, const float* __restrict__ b, long n)
{
    long stride = (long)gridDim.x * blockDim.x;
    for (long i = (long)blockIdx.x * blockDim.x + threadIdx.x; i < n; i += stride)
        C[i] = b[(int)(i % 200)];
}

// r_out[400,200] = R[400,200] @ W[200,200]
__global__ __launch_bounds__(256) void rel_mm(
    const float* __restrict__ R, const float* __restrict__ W, float* __restrict__ O)
{
    int idx = blockIdx.x * blockDim.x + threadIdx.x;
    if (idx >= 400 * 200) return;
    int row = idx / 200, col = idx - row * 200;
    float acc = 0.f;
    for (int k = 0; k < 200; ++k) acc = fmaf(R[row * 200 + k], W[k * 200 + col], acc);
    O[idx] = acc;
}

// build stk [B,400] (sub_emb | rel_emb) + bn0 scalar stats
__global__ __launch_bounds__(256) void build_stk(
    const float* __restrict__ x2, const float* __restrict__ r2,
    const int* __restrict__ subj, const int* __restrict__ ridx,
    float* __restrict__ stk, double* __restrict__ s1, double* __restrict__ s2)
{
    int b = blockIdx.x, t = threadIdx.x;
    const float* se = x2 + (size_t)subj[b] * DIM;
    const float* re = r2 + (size_t)ridx[b] * DIM;
    float sum = 0.f, sq = 0.f;
    for (int i = t; i < 400; i += 256) {
        float v = (i < 200) ? se[i] : re[i - 200];
        stk[(size_t)b * 400 + i] = v;
        sum += v; sq += v * v;
    }
    for (int off = 32; off > 0; off >>= 1) {
        sum += __shfl_down(sum, off);
        sq  += __shfl_down(sq, off);
    }
    if ((t & 63) == 0) { gAtomicAdd(&s1[0], (double)sum); gAtomicAdd(&s2[0], (double)sq); }
}

// conv 7x7 valid, 1->200 ch, input bn0-affine applied; writes raw conv+bias to P and bn1 stats
__global__ __launch_bounds__(256) void conv_fwd(
    const float* __restrict__ stk, const float* __restrict__ conv_w,
    const float* __restrict__ conv_b, const float* __restrict__ sc0,
    const float* __restrict__ sh0, float* __restrict__ P,
    double* __restrict__ s1, double* __restrict__ s2)
{
    __shared__ float img[400];
    __shared__ float wsm[9800];
    __shared__ float bsm[200];
    __shared__ float fsum[200];
    __shared__ float fsq[200];
    int b = blockIdx.x, t = threadIdx.x;
    float scale0 = sc0[0], shift0 = sh0[0];
    if (t < 200) { fsum[t] = 0.f; fsq[t] = 0.f; bsm[t] = conv_b[t]; }
    for (int i = t; i < 400; i += 256) img[i] = stk[(size_t)b * 400 + i] * scale0 + shift0;
    for (int i = t; i < 9800; i += 256) wsm[i] = conv_w[i];
    __syncthreads();
    for (int fy = t; fy < 2800; fy += 256) {
        int f = fy / 14, y = fy - (fy / 14) * 14;
        const float* wf = &wsm[f * 49];
        float acc[14];
        float bias = bsm[f];
#pragma unroll
        for (int xx = 0; xx < 14; ++xx) acc[xx] = bias;
#pragma unroll
        for (int i = 0; i < 7; ++i) {
            const float* rowp = &img[(y + i) * 20];
            float rv[20];
#pragma unroll
            for (int c = 0; c < 20; ++c) rv[c] = rowp[c];
#pragma unroll
            for (int j = 0; j < 7; ++j) {
                float wv = wf[i * 7 + j];
#pragma unroll
                for (int xx = 0; xx < 14; ++xx) acc[xx] = fmaf(rv[xx + j], wv, acc[xx]);
            }
        }
        float ls = 0.f, lq = 0.f;
        float* pp = P + (size_t)b * FLATSZ + (size_t)f * 196 + y * 14;
#pragma unroll
        for (int xx = 0; xx < 14; ++xx) {
            float v = acc[xx];
            pp[xx] = v;
            ls += v; lq += v * v;
        }
        atomicAdd(&fsum[f], ls);
        atomicAdd(&fsq[f], lq);
    }
    __syncthreads();
    if (t < 200) {
        gAtomicAdd(&s1[t], (double)fsum[t]);
        gAtomicAdd(&s2[t], (double)fsq[t]);
    }
}

// bn1 + relu in place on P [B, 39200], channel f = k/196
__global__ __launch_bounds__(256) void bn1_relu(
    float* __restrict__ P, const float* __restrict__ sc, const float* __restrict__ sh)
{
    long n4 = (long)NB * (FLATSZ / 4);
    long stride = (long)gridDim.x * blockDim.x;
    for (long i = (long)blockIdx.x * blockDim.x + threadIdx.x; i < n4; i += stride) {
        int k4 = (int)(i % (FLATSZ / 4));
        int f = k4 / 49;                   // 49 float4s per channel (196/4)
        float s = sc[f], h = sh[f];
        float4 v = ((const float4*)P)[i];
        v.x = fmaxf(v.x * s + h, 0.f);
        v.y = fmaxf(v.y * s + h, 0.f);
        v.z = fmaxf(v.z * s + h, 0.f);
        v.w = fmaxf(v.w * s + h, 0.f);
        ((float4*)P)[i] = v;
    }
}

// fc_w [200, 39200] -> WT [39200, 200]
__global__ __launch_bounds__(256) void transpose_fcw(
    const float* __restrict__ W, float* __restrict__ WT)
{
    __shared__ float tile[32][33];
    int k0 = blockIdx.x * 32, o0 = blockIdx.y * 32;
    int tx = threadIdx.x & 31, ty = threadIdx.x >> 5;
    for (int i = ty; i < 32; i += 8) {
        int o = o0 + i, k = k0 + tx;
        tile[i][tx] = (o < 200 && k < FLATSZ) ? W[(size_t)o * FLATSZ + k] : 0.f;
    }
    __syncthreads();
    for (int i = ty; i < 32; i += 8) {
        int k = k0 + i, o = o0 + tx;
        if (k < FLATSZ && o < 200) WT[(size_t)k * 200 + o] = tile[tx][i];
    }
}

// out[b,j] = sigmoid( sum_d Hn[b,d] * x2[obj[j], d] )
__global__ __launch_bounds__(256) void score_mm(
    const float* __restrict__ Hn, const float* __restrict__ x2,
    const int* __restrict__ obj, float* __restrict__ out)
{
    __shared__ float Asm[16][17];
    __shared__ float Bsm[16][17];
    int tx = threadIdx.x & 15, ty = threadIdx.x >> 4;
    int row = blockIdx.y * 16 + ty;      // b
    int col = blockIdx.x * 16 + tx;      // j
    int oj = obj[blockIdx.x * 16 + ty];
    float acc = 0.f;
    for (int k0 = 0; k0 < 200; k0 += 16) {
        int k = k0 + tx;
        Asm[ty][tx] = (k < 200) ? Hn[(size_t)row * 200 + k] : 0.f;
        Bsm[ty][tx] = (k < 200) ? x2[(size_t)oj * 200 + k] : 0.f;
        __syncthreads();
#pragma unroll
        for (int kk = 0; kk < 16; ++kk) acc = fmaf(Asm[ty][kk], Bsm[tx][kk], acc);
        __syncthreads();
    }
    out[(size_t)row * NB + col] = 1.f / (1.f + expf(-acc));
}

// ---------------------------------------------------------------- driver
extern "C" void kernel_launch(void* const* d_in, const int* in_sizes, int n_in,
                              void* d_out, int out_size, void* d_ws, size_t ws_size,
                              hipStream_t stream)
{
    (void)in_sizes; (void)n_in; (void)out_size;
    const float* init_embed = (const float*)d_in[0];
    const float* init_rel   = (const float*)d_in[1];
    const float* edge_norm  = (const float*)d_in[2];
    const float* w_in1  = (const float*)d_in[3];
    const float* w_out1 = (const float*)d_in[4];
    const float* w_loop1= (const float*)d_in[5];
    const float* w_rel1 = (const float*)d_in[6];
    const float* lrel1  = (const float*)d_in[7];
    const float* b1     = (const float*)d_in[8];
    const float* gm1    = (const float*)d_in[9];
    const float* be1    = (const float*)d_in[10];
    const float* w_in2  = (const float*)d_in[11];
    const float* w_out2 = (const float*)d_in[12];
    const float* w_loop2= (const float*)d_in[13];
    const float* w_rel2 = (const float*)d_in[14];
    const float* lrel2  = (const float*)d_in[15];
    const float* b2     = (const float*)d_in[16];
    const float* gm2    = (const float*)d_in[17];
    const float* be2    = (const float*)d_in[18];
    const float* conv_w = (const float*)d_in[19];
    const float* conv_b = (const float*)d_in[20];
    const float* fc_w   = (const float*)d_in[21];
    const float* fc_b   = (const float*)d_in[22];
    const float* bn0_g  = (const float*)d_in[23];
    const float* bn0_b  = (const float*)d_in[24];
    const float* bn1_g  = (const float*)d_in[25];
    const float* bn1_b  = (const float*)d_in[26];
    const float* bn2_g  = (const float*)d_in[27];
    const float* bn2_b  = (const float*)d_in[28];
    const int* subj   = (const int*)d_in[29];
    const int* relidx = (const int*)d_in[30];
    const int* obj    = (const int*)d_in[31];
    const int* src    = (const int*)d_in[32];
    const int* dst    = (const int*)d_in[33];
    const int* etype  = (const int*)d_in[34];

    float* ws = (float*)d_ws;
    float* x1  = ws;                       // region 0
    float* agg = ws + REGF;                // region 1
    float* x2  = ws + 2 * REGF;            // region 2 (lives through the ConvE head)
    float* r1v = ws + 3 * REGF;            // tail
    float* r2v = r1v + 80000;
    float* stk = r2v + 80000;              // [B,400]
    float* hfc = stk + 409600;             // [B,200]
    float* fsc = hfc + 204800;             // scale[256]
    float* fsh = fsc + 256;                // shift[256]
    double* ds1 = (double*)(fsh + 256);    // 256 doubles (offset is even -> 8B aligned)
    double* ds2 = ds1 + 256;
    float* fcwT = (float*)(ds2 + 256);     // [39200,200]
    float* P = ws;                         // conv output [B,39200] overlays dead x1+agg

    const size_t NEED = (3 * REGF + 80000 + 80000 + 409600 + 204800 + 512 + 1024 + 7840000)
                        * sizeof(float);
    if (ws_size < NEED) return;            // workspace too small -> clean numeric failure

    dim3 gGemm((NENT + 127) / 128, 1);

    // -------- one CompGCN layer --------
    auto run_layer = [&](const float* xin, const float* rin,
                         const float* wi, const float* wo, const float* wl,
                         const float* wr, const float* lrel, const float* bias,
                         const float* gg, const float* bbeta,
                         float* hout, float* rout) {
        hipMemsetAsync(agg, 0, NDF * sizeof(float), stream);
        scatter_edges<<<NEDGE / 8, 256, 0, stream>>>(xin, rin, edge_norm, src, dst, etype,
                                                     agg, 0, NEDGE / 2);
        init_bias200<<<8192, 256, 0, stream>>>(hout, bias, (long)NDF);
        gemm_n200<<<gGemm, 256, 0, stream>>>(agg, 200, wi, hout, NENT, 200, 200,
                                             1.f / 3.f, nullptr, 0);
        hipMemsetAsync(agg, 0, NDF * sizeof(float), stream);
        scatter_edges<<<NEDGE / 8, 256, 0, stream>>>(xin, rin, edge_norm, src, dst, etype,
                                                     agg, NEDGE / 2, NEDGE);
        gemm_n200<<<gGemm, 256, 0, stream>>>(agg, 200, wo, hout, NENT, 200, 200,
                                             1.f / 3.f, nullptr, 0);
        gemm_n200<<<gGemm, 256, 0, stream>>>(xin, 200, wl, hout, NENT, 200, 200,
                                             1.f / 3.f, lrel, 0);
        hipMemsetAsync(ds1, 0, 512 * sizeof(double), stream);
        colstats<<<(NENT + 499) / 500, 256, 0, stream>>>(hout, NENT, 500, ds1, ds2);
        finalize_stats<<<1, 256, 0, stream>>>(ds1, ds2, gg, bbeta, fsc, fsh, 200, (double)NENT);
        bn_act_200<<<4096, 256, 0, stream>>>(hout, fsc, fsh, (long)NENT * 50, 0);
        rel_mm<<<(80000 + 255) / 256, 256, 0, stream>>>(rin, wr, rout);
    };

    run_layer(init_embed, init_rel, w_in1, w_out1, w_loop1, w_rel1, lrel1, b1, gm1, be1, x1, r1v);
    run_layer(x1, r1v, w_in2, w_out2, w_loop2, w_rel2, lrel2, b2, gm2, be2, x2, r2v);

    // -------- ConvE head --------
    hipMemsetAsync(ds1, 0, 512 * sizeof(double), stream);
    build_stk<<<NB, 256, 0, stream>>>(x2, r2v, subj, relidx, stk, ds1, ds2);
    finalize_stats<<<1, 256, 0, stream>>>(ds1, ds2, bn0_g, bn0_b, fsc, fsh, 1,
                                          (double)((long)NB * 400));
    hipMemsetAsync(ds1, 0, 512 * sizeof(double), stream);
    conv_fwd<<<NB, 256, 0, stream>>>(stk, conv_w, conv_b, fsc, fsh, P, ds1, ds2);
    finalize_stats<<<1, 256, 0, stream>>>(ds1, ds2, bn1_g, bn1_b, fsc, fsh, 200,
                                          (double)((long)NB * 196));
    bn1_relu<<<8192, 256, 0, stream>>>(P, fsc, fsh);
    transpose_fcw<<<dim3(FLATSZ / 32, 7), 256, 0, stream>>>(fc_w, fcwT);
    init_bias200<<<800, 256, 0, stream>>>(hfc, fc_b, (long)NB * 200);
    gemm_n200<<<dim3(8, 32), 256, 0, stream>>>(P, FLATSZ, fcwT, hfc, NB, FLATSZ, 1225,
                                               1.f, nullptr, 1);
    hipMemsetAsync(ds1, 0, 512 * sizeof(double), stream);
    colstats<<<4, 256, 0, stream>>>(hfc, NB, 256, ds1, ds2);
    finalize_stats<<<1, 256, 0, stream>>>(ds1, ds2, bn2_g, bn2_b, fsc, fsh, 200, (double)NB);
    bn_act_200<<<200, 256, 0, stream>>>(hfc, fsc, fsh, (long)NB * 50, 1);
    score_mm<<<dim3(NB / 16, NB / 16), 256, 0, stream>>>(hfc, x2, obj, (float*)d_out);
}

// Round 3
// 6946.362 us; speedup vs baseline: 1.3627x; 1.3627x over previous
//
#include <hip/hip_runtime.h>

#define DIM 200
#define NENT 100000
#define NEDGE 1000000
#define NB 1024
#define NFILT 200
#define FLATSZ 39200

#define NDF ((size_t)NENT * DIM)      /* 20,000,000 floats per node matrix */
#define REGF ((size_t)20100000)       /* region stride in floats */
#define WPLANE (208 * 224)            /* one packed weight plane (3 segs each) */

typedef float floatx4 __attribute__((ext_vector_type(4)));
typedef short bf16x8 __attribute__((ext_vector_type(8)));
typedef _Float16 halfx8 __attribute__((ext_vector_type(8)));
typedef _Float16 halfx4 __attribute__((ext_vector_type(4)));

__device__ __forceinline__ void gAtomicAdd(float* p, float v) { unsafeAtomicAdd(p, v); }
__device__ __forceinline__ void gAtomicAdd(double* p, double v) { unsafeAtomicAdd(p, v); }

__device__ __forceinline__ short f2bf(float f) {
    union { float f; unsigned u; } v; v.f = f;
    unsigned r = v.u + 0x7fffu + ((v.u >> 16) & 1u);
    return (short)(r >> 16);
}
__device__ __forceinline__ float bf2f(short s) {
    union { float f; unsigned u; } v; v.u = ((unsigned)(unsigned short)s) << 16;
    return v.f;
}

// split v into bf16 hi/lo such that hi+lo ~ v with ~17-bit precision
__device__ __forceinline__ void split8(const floatx4& lo4, const floatx4& hi4,
                                       bf16x8& h, bf16x8& l) {
#pragma unroll
    for (int e = 0; e < 4; ++e) {
        short hh = f2bf(lo4[e]); h[e] = hh; l[e] = f2bf(lo4[e] - bf2f(hh));
        short hh2 = f2bf(hi4[e]); h[e + 4] = hh2; l[e + 4] = f2bf(hi4[e] - bf2f(hh2));
    }
}

// ---------------------------------------------------------------- scatter
__global__ __launch_bounds__(256) void scatter_edges(
    const float* __restrict__ x, const float* __restrict__ r,
    const float* __restrict__ enorm, const int* __restrict__ src,
    const int* __restrict__ dst, const int* __restrict__ etype,
    float* __restrict__ agg, int e0, int e1)
{
    int e = e0 + blockIdx.x * 4 + (threadIdx.x >> 6);
    int lane = threadIdx.x & 63;
    if (e >= e1) return;
    int s = src[e], d = dst[e], t = etype[e];
    float en = enorm[e];
    if (lane < 50) {
        const float4* xs = (const float4*)(x + (size_t)s * DIM);
        const float4* rs = (const float4*)(r + (size_t)t * DIM);
        float4 xv = xs[lane], rv = rs[lane];
        float* ad = agg + (size_t)d * DIM + lane * 4;
        gAtomicAdd(ad + 0, xv.x * rv.x * en);
        gAtomicAdd(ad + 1, xv.y * rv.y * en);
        gAtomicAdd(ad + 2, xv.z * rv.z * en);
        gAtomicAdd(ad + 3, xv.w * rv.w * en);
    }
}

// ---------------------------------------------------------------- weight packing
// hi plane at Wp[0..3*WPLANE), lo plane at Wp[3*WPLANE..6*WPLANE)
__global__ __launch_bounds__(256) void pack_w3(
    const float* __restrict__ w0, const float* __restrict__ w1,
    const float* __restrict__ w2, short* __restrict__ Wp)
{
    int i = blockIdx.x * 256 + threadIdx.x;
    if (i >= 3 * WPLANE) return;
    int seg = i / WPLANE, rem = i % WPLANE;
    int n = rem / 224, k = rem % 224;
    const float* W = (seg == 0) ? w0 : (seg == 1) ? w1 : w2;
    float v = (n < 200 && k < 200) ? W[k * 200 + n] : 0.f;
    short hi = f2bf(v);
    Wp[i] = hi;
    Wp[i + 3 * WPLANE] = f2bf(v - bf2f(hi));
}

// fp16 fc weights: Wt[n:208][k:39200] = fc_w[n][k], rows >=200 zero
__global__ __launch_bounds__(256) void pack_fcw(
    const float* __restrict__ W, _Float16* __restrict__ Wt)
{
    long i = (long)blockIdx.x * 256 + threadIdx.x;
    if (i >= (long)208 * FLATSZ) return;
    int n = (int)(i / FLATSZ);
    Wt[i] = (n < 200) ? (_Float16)W[i] : (_Float16)0.f;
}

// ---------------------------------------------------------------- split-bf16 MFMA GEMM
// C[M,200] = alpha*(sum_seg A_seg @ W_seg) (+bias on first write | += C)
__global__ __launch_bounds__(256) void gemm_mfma(
    const float* __restrict__ A0, const float* __restrict__ A1,
    const float* __restrict__ scale1, const short* __restrict__ WpH,
    const short* __restrict__ WpL,
    float* __restrict__ C, const float* __restrict__ bias,
    float alpha, int M, int nseg)
{
    __shared__ short BsH[208 * 40];
    __shared__ short BsL[208 * 40];
    int t = threadIdx.x;
    int lane = t & 63, wave = t >> 6;
    int col16 = lane & 15, quad = lane >> 4;
    int row_base = blockIdx.x * 128 + wave * 32;
    floatx4 acc[13][2];
#pragma unroll
    for (int nf = 0; nf < 13; ++nf) { acc[nf][0] = (floatx4)0.f; acc[nf][1] = (floatx4)0.f; }
    int r0 = row_base + col16, r1 = row_base + 16 + col16;
    int r0c = min(r0, M - 1), r1c = min(r1, M - 1);

    for (int seg = 0; seg < nseg; ++seg) {
        const float* Ap = (seg == 0) ? A0 : A1;
        const float* sc = (seg == 0) ? nullptr : scale1;
        const short* WH = WpH + seg * WPLANE;
        const short* WL = WpL + seg * WPLANE;
        for (int c = 0; c < 7; ++c) {
            int k0 = c * 32;
            for (int i = t; i < 208 * 4; i += 256) {
                int n = i >> 2, part = i & 3;
                *(bf16x8*)&BsH[n * 40 + part * 8] = *(const bf16x8*)&WH[n * 224 + k0 + part * 8];
                *(bf16x8*)&BsL[n * 40 + part * 8] = *(const bf16x8*)&WL[n * 224 + k0 + part * 8];
            }
            __syncthreads();
            int koff = k0 + quad * 8;
            bf16x8 a0h, a0l, a1h, a1l;
            if (koff < 200) {
                floatx4 lo0 = *(const floatx4*)&Ap[(size_t)r0c * 200 + koff];
                floatx4 hi0 = *(const floatx4*)&Ap[(size_t)r0c * 200 + koff + 4];
                floatx4 lo1 = *(const floatx4*)&Ap[(size_t)r1c * 200 + koff];
                floatx4 hi1 = *(const floatx4*)&Ap[(size_t)r1c * 200 + koff + 4];
                if (sc) {
                    floatx4 slo = *(const floatx4*)&sc[koff];
                    floatx4 shi = *(const floatx4*)&sc[koff + 4];
                    lo0 *= slo; hi0 *= shi; lo1 *= slo; hi1 *= shi;
                }
                split8(lo0, hi0, a0h, a0l);
                split8(lo1, hi1, a1h, a1l);
            } else {
                a0h = (bf16x8)0; a0l = (bf16x8)0; a1h = (bf16x8)0; a1l = (bf16x8)0;
            }
#pragma unroll
            for (int nf = 0; nf < 13; ++nf) {
                bf16x8 bh = *(const bf16x8*)&BsH[(nf * 16 + col16) * 40 + quad * 8];
                bf16x8 bl = *(const bf16x8*)&BsL[(nf * 16 + col16) * 40 + quad * 8];
                acc[nf][0] = __builtin_amdgcn_mfma_f32_16x16x32_bf16(a0h, bh, acc[nf][0], 0, 0, 0);
                acc[nf][0] = __builtin_amdgcn_mfma_f32_16x16x32_bf16(a0h, bl, acc[nf][0], 0, 0, 0);
                acc[nf][0] = __builtin_amdgcn_mfma_f32_16x16x32_bf16(a0l, bh, acc[nf][0], 0, 0, 0);
                acc[nf][1] = __builtin_amdgcn_mfma_f32_16x16x32_bf16(a1h, bh, acc[nf][1], 0, 0, 0);
                acc[nf][1] = __builtin_amdgcn_mfma_f32_16x16x32_bf16(a1h, bl, acc[nf][1], 0, 0, 0);
                acc[nf][1] = __builtin_amdgcn_mfma_f32_16x16x32_bf16(a1l, bh, acc[nf][1], 0, 0, 0);
            }
            __syncthreads();
        }
    }
#pragma unroll
    for (int nf = 0; nf < 13; ++nf) {
        int colg = nf * 16 + col16;
        if (colg >= 200) continue;
        float bv = bias ? bias[colg] : 0.f;
#pragma unroll
        for (int h = 0; h < 2; ++h) {
            int rbase = row_base + h * 16 + quad * 4;
#pragma unroll
            for (int j = 0; j < 4; ++j) {
                int rr = rbase + j;
                if (rr < M) {
                    size_t idx = (size_t)rr * 200 + colg;
                    float v = acc[nf][h][j] * alpha + bv;
                    if (bias) C[idx] = v; else C[idx] += v;
                }
            }
        }
    }
}

// ---------------------------------------------------------------- fc MFMA GEMM (fp16), split-K, atomic accumulate
__global__ __launch_bounds__(256) void fc_gemm(
    const _Float16* __restrict__ Ph, const _Float16* __restrict__ Wt,
    float* __restrict__ C)
{
    __shared__ _Float16 Bs[208 * 40];
    int t = threadIdx.x;
    int lane = t & 63, wave = t >> 6;
    int col16 = lane & 15, quad = lane >> 4;
    int row_base = blockIdx.x * 128 + wave * 32;
    int c0 = blockIdx.y * 25;
    floatx4 acc[13][2];
#pragma unroll
    for (int nf = 0; nf < 13; ++nf) { acc[nf][0] = (floatx4)0.f; acc[nf][1] = (floatx4)0.f; }
    int r0 = row_base + col16, r1 = row_base + 16 + col16;

    for (int c = c0; c < c0 + 25; ++c) {
        int k0 = c * 32;
        for (int i = t; i < 208 * 4; i += 256) {
            int n = i >> 2, part = i & 3;
            *(halfx8*)&Bs[n * 40 + part * 8] =
                *(const halfx8*)&Wt[(size_t)n * FLATSZ + k0 + part * 8];
        }
        __syncthreads();
        int koff = k0 + quad * 8;
        halfx8 a0 = *(const halfx8*)&Ph[(size_t)r0 * FLATSZ + koff];
        halfx8 a1 = *(const halfx8*)&Ph[(size_t)r1 * FLATSZ + koff];
#pragma unroll
        for (int nf = 0; nf < 13; ++nf) {
            halfx8 b = *(const halfx8*)&Bs[(nf * 16 + col16) * 40 + quad * 8];
            acc[nf][0] = __builtin_amdgcn_mfma_f32_16x16x32_f16(a0, b, acc[nf][0], 0, 0, 0);
            acc[nf][1] = __builtin_amdgcn_mfma_f32_16x16x32_f16(a1, b, acc[nf][1], 0, 0, 0);
        }
        __syncthreads();
    }
#pragma unroll
    for (int nf = 0; nf < 13; ++nf) {
        int colg = nf * 16 + col16;
        if (colg >= 200) continue;
#pragma unroll
        for (int h = 0; h < 2; ++h) {
            int rbase = row_base + h * 16 + quad * 4;
#pragma unroll
            for (int j = 0; j < 4; ++j)
                gAtomicAdd(&C[(size_t)(rbase + j) * 200 + colg], acc[nf][h][j]);
        }
    }
}

// ---------------------------------------------------------------- stats / bn
__global__ __launch_bounds__(256) void colstats(
    const float* __restrict__ X, int M, int rpb,
    double* __restrict__ s1, double* __restrict__ s2)
{
    int c = threadIdx.x;
    if (c >= 200) return;
    int r0 = blockIdx.x * rpb;
    int r1 = min(r0 + rpb, M);
    float sum = 0.f, sq = 0.f;
    for (int rr = r0; rr < r1; ++rr) {
        float v = X[(size_t)rr * 200 + c];
        sum += v; sq += v * v;
    }
    gAtomicAdd(&s1[c], (double)sum);
    gAtomicAdd(&s2[c], (double)sq);
}

__global__ void finalize_stats(const double* __restrict__ s1, const double* __restrict__ s2,
                               const float* __restrict__ g, const float* __restrict__ bb,
                               float* __restrict__ sc, float* __restrict__ sh,
                               int ncols, double count)
{
    int c = threadIdx.x;
    if (c >= ncols) return;
    double m = s1[c] / count;
    double v = s2[c] / count - m * m;
    double scd = (double)g[c] / sqrt(v + 1e-5);
    sc[c] = (float)scd;
    sh[c] = (float)((double)bb[c] - m * scd);
}

__global__ __launch_bounds__(256) void bn_act_200(
    float* __restrict__ X, const float* __restrict__ sc, const float* __restrict__ sh,
    long n4, int act)
{
    long stride = (long)gridDim.x * blockDim.x;
    for (long i = (long)blockIdx.x * blockDim.x + threadIdx.x; i < n4; i += stride) {
        int c4 = (int)(i % 50) * 4;
        float4 v = ((const float4*)X)[i];
        float a0 = v.x * sc[c4 + 0] + sh[c4 + 0];
        float a1 = v.y * sc[c4 + 1] + sh[c4 + 1];
        float a2 = v.z * sc[c4 + 2] + sh[c4 + 2];
        float a3 = v.w * sc[c4 + 3] + sh[c4 + 3];
        if (act == 0) { a0 = tanhf(a0); a1 = tanhf(a1); a2 = tanhf(a2); a3 = tanhf(a3); }
        else { a0 = fmaxf(a0, 0.f); a1 = fmaxf(a1, 0.f); a2 = fmaxf(a2, 0.f); a3 = fmaxf(a3, 0.f); }
        ((float4*)X)[i] = make_float4(a0, a1, a2, a3);
    }
}

__global__ __launch_bounds__(256) void init_bias200(
    float* __restrict__ C, const float* __restrict__ b, long n)
{
    long stride = (long)gridDim.x * blockDim.x;
    for (long i = (long)blockIdx.x * blockDim.x + threadIdx.x; i < n; i += stride)
        C[i] = b[(int)(i % 200)];
}

__global__ __launch_bounds__(256) void rel_mm(
    const float* __restrict__ R, const float* __restrict__ W, float* __restrict__ O)
{
    int idx = blockIdx.x * blockDim.x + threadIdx.x;
    if (idx >= 200 * 200) return;
    int row = idx / 200, col = idx - row * 200;
    float acc = 0.f;
    for (int k = 0; k < 200; ++k) acc = fmaf(R[row * 200 + k], W[k * 200 + col], acc);
    O[idx] = acc;
}

__global__ __launch_bounds__(256) void build_stk(
    const float* __restrict__ x2, const float* __restrict__ r2,
    const int* __restrict__ subj, const int* __restrict__ ridx,
    float* __restrict__ stk, double* __restrict__ s1, double* __restrict__ s2)
{
    int b = blockIdx.x, t = threadIdx.x;
    const float* se = x2 + (size_t)subj[b] * DIM;
    const float* re = r2 + (size_t)ridx[b] * DIM;
    float sum = 0.f, sq = 0.f;
    for (int i = t; i < 400; i += 256) {
        float v = (i < 200) ? se[i] : re[i - 200];
        stk[(size_t)b * 400 + i] = v;
        sum += v; sq += v * v;
    }
    for (int off = 32; off > 0; off >>= 1) {
        sum += __shfl_down(sum, off);
        sq  += __shfl_down(sq, off);
    }
    if ((t & 63) == 0) { gAtomicAdd(&s1[0], (double)sum); gAtomicAdd(&s2[0], (double)sq); }
}

// conv 7x7 valid; writes conv+bias as fp16 to Ph and accumulates bn1 stats
__global__ __launch_bounds__(256) void conv_fwd(
    const float* __restrict__ stk, const float* __restrict__ conv_w,
    const float* __restrict__ conv_b, const float* __restrict__ sc0,
    const float* __restrict__ sh0, _Float16* __restrict__ Ph,
    double* __restrict__ s1, double* __restrict__ s2)
{
    __shared__ float img[400];
    __shared__ float wsm[9800];
    __shared__ float bsm[200];
    __shared__ float fsum[200];
    __shared__ float fsq[200];
    int b = blockIdx.x, t = threadIdx.x;
    float scale0 = sc0[0], shift0 = sh0[0];
    if (t < 200) { fsum[t] = 0.f; fsq[t] = 0.f; bsm[t] = conv_b[t]; }
    for (int i = t; i < 400; i += 256) img[i] = stk[(size_t)b * 400 + i] * scale0 + shift0;
    for (int i = t; i < 9800; i += 256) wsm[i] = conv_w[i];
    __syncthreads();
    for (int fy = t; fy < 2800; fy += 256) {
        int f = fy / 14, y = fy - (fy / 14) * 14;
        const float* wf = &wsm[f * 49];
        float acc[14];
        float bias = bsm[f];
#pragma unroll
        for (int xx = 0; xx < 14; ++xx) acc[xx] = bias;
#pragma unroll
        for (int i = 0; i < 7; ++i) {
            const float* rowp = &img[(y + i) * 20];
            float rv[20];
#pragma unroll
            for (int c = 0; c < 20; ++c) rv[c] = rowp[c];
#pragma unroll
            for (int j = 0; j < 7; ++j) {
                float wv = wf[i * 7 + j];
#pragma unroll
                for (int xx = 0; xx < 14; ++xx) acc[xx] = fmaf(rv[xx + j], wv, acc[xx]);
            }
        }
        float ls = 0.f, lq = 0.f;
        _Float16* pp = Ph + (size_t)b * FLATSZ + (size_t)f * 196 + y * 14;
#pragma unroll
        for (int xx = 0; xx < 14; ++xx) {
            float v = acc[xx];
            pp[xx] = (_Float16)v;
            ls += v; lq += v * v;
        }
        atomicAdd(&fsum[f], ls);
        atomicAdd(&fsq[f], lq);
    }
    __syncthreads();
    if (t < 200) {
        gAtomicAdd(&s1[t], (double)fsum[t]);
        gAtomicAdd(&s2[t], (double)fsq[t]);
    }
}

// bn1 + relu in place on fp16 Ph [B, 39200]; channel f = (i%9800)/49
__global__ __launch_bounds__(256) void bn1_relu_f16(
    _Float16* __restrict__ Ph, const float* __restrict__ sc, const float* __restrict__ sh)
{
    long n4 = (long)NB * (FLATSZ / 4);
    long stride = (long)gridDim.x * blockDim.x;
    for (long i = (long)blockIdx.x * blockDim.x + threadIdx.x; i < n4; i += stride) {
        int k4 = (int)(i % (FLATSZ / 4));
        int f = k4 / 49;
        float s = sc[f], h = sh[f];
        halfx4 v = ((const halfx4*)Ph)[i];
#pragma unroll
        for (int e = 0; e < 4; ++e) {
            float x = (float)v[e];
            x = fmaxf(x * s + h, 0.f);
            v[e] = (_Float16)x;
        }
        ((halfx4*)Ph)[i] = v;
    }
}

__global__ __launch_bounds__(256) void score_mm(
    const float* __restrict__ Hn, const float* __restrict__ x2,
    const int* __restrict__ obj, float* __restrict__ out)
{
    __shared__ float Asm[16][17];
    __shared__ float Bsm[16][17];
    int tx = threadIdx.x & 15, ty = threadIdx.x >> 4;
    int row = blockIdx.y * 16 + ty;
    int col = blockIdx.x * 16 + tx;
    int oj = obj[blockIdx.x * 16 + ty];
    float acc = 0.f;
    for (int k0 = 0; k0 < 200; k0 += 16) {
        int k = k0 + tx;
        Asm[ty][tx] = (k < 200) ? Hn[(size_t)row * 200 + k] : 0.f;
        Bsm[ty][tx] = (k < 200) ? x2[(size_t)oj * 200 + k] : 0.f;
        __syncthreads();
#pragma unroll
        for (int kk = 0; kk < 16; ++kk) acc = fmaf(Asm[ty][kk], Bsm[tx][kk], acc);
        __syncthreads();
    }
    out[(size_t)row * NB + col] = 1.f / (1.f + expf(-acc));
}

// ---------------------------------------------------------------- driver
extern "C" void kernel_launch(void* const* d_in, const int* in_sizes, int n_in,
                              void* d_out, int out_size, void* d_ws, size_t ws_size,
                              hipStream_t stream)
{
    (void)in_sizes; (void)n_in; (void)out_size;
    const float* init_embed = (const float*)d_in[0];
    const float* init_rel   = (const float*)d_in[1];
    const float* edge_norm  = (const float*)d_in[2];
    const float* w_in1  = (const float*)d_in[3];
    const float* w_out1 = (const float*)d_in[4];
    const float* w_loop1= (const float*)d_in[5];
    const float* w_rel1 = (const float*)d_in[6];
    const float* lrel1  = (const float*)d_in[7];
    const float* b1     = (const float*)d_in[8];
    const float* gm1    = (const float*)d_in[9];
    const float* be1    = (const float*)d_in[10];
    const float* w_in2  = (const float*)d_in[11];
    const float* w_out2 = (const float*)d_in[12];
    const float* w_loop2= (const float*)d_in[13];
    const float* w_rel2 = (const float*)d_in[14];
    const float* lrel2  = (const float*)d_in[15];
    const float* b2     = (const float*)d_in[16];
    const float* gm2    = (const float*)d_in[17];
    const float* be2    = (const float*)d_in[18];
    const float* conv_w = (const float*)d_in[19];
    const float* conv_b = (const float*)d_in[20];
    const float* fc_w   = (const float*)d_in[21];
    const float* fc_b   = (const float*)d_in[22];
    const float* bn0_g  = (const float*)d_in[23];
    const float* bn0_b  = (const float*)d_in[24];
    const float* bn1_g  = (const float*)d_in[25];
    const float* bn1_b  = (const float*)d_in[26];
    const float* bn2_g  = (const float*)d_in[27];
    const float* bn2_b  = (const float*)d_in[28];
    const int* subj   = (const int*)d_in[29];
    const int* relidx = (const int*)d_in[30];
    const int* obj    = (const int*)d_in[31];
    const int* src    = (const int*)d_in[32];
    const int* dst    = (const int*)d_in[33];
    const int* etype  = (const int*)d_in[34];

    float* ws = (float*)d_ws;
    float* x1  = ws;                       // region 0 (later: Ph fp16 conv output)
    float* agg = ws + REGF;                // region 1 (later: fp16 fc weights)
    float* x2  = ws + 2 * REGF;            // region 2 (alive through head)
    float* r1v = ws + 3 * REGF;            // tail
    float* r2v = r1v + 40000;
    float* stk = r2v + 40000;              // [B,400]
    float* hfc = stk + 409600;             // [B,200]
    float* fsc = hfc + 204800;
    float* fsh = fsc + 256;
    double* ds1 = (double*)(fsh + 256);    // 256 doubles
    double* ds2 = ds1 + 256;
    short* Wp = (short*)(ds2 + 256);       // 6*WPLANE bf16 (hi then lo)
    _Float16* Ph  = (_Float16*)x1;         // [1024][39200] fp16 (region 0, after layers)
    _Float16* fch = (_Float16*)agg;        // [208][39200] fp16 (region 1, after layers)

    const size_t NEED = (3 * REGF + 40000 + 40000 + 409600 + 204800 + 512 + 1024
                         + (6 * WPLANE) / 2 + 64) * sizeof(float);
    if (ws_size < NEED) return;

    // -------- one CompGCN layer --------
    auto run_layer = [&](const float* xin, const float* rin,
                         const float* wi, const float* wo, const float* wl,
                         const float* wr, const float* lrel, const float* bias,
                         const float* gg, const float* bbeta,
                         float* hout, float* rout) {
        pack_w3<<<(3 * WPLANE + 255) / 256, 256, 0, stream>>>(wi, wo, wl, Wp);
        hipMemsetAsync(agg, 0, NDF * sizeof(float), stream);
        scatter_edges<<<NEDGE / 8, 256, 0, stream>>>(xin, rin, edge_norm, src, dst, etype,
                                                     agg, 0, NEDGE / 2);
        gemm_mfma<<<(NENT + 127) / 128, 256, 0, stream>>>(
            agg, nullptr, nullptr, Wp, Wp + 3 * WPLANE, hout, bias, 1.f / 3.f, NENT, 1);
        hipMemsetAsync(agg, 0, NDF * sizeof(float), stream);
        scatter_edges<<<NEDGE / 8, 256, 0, stream>>>(xin, rin, edge_norm, src, dst, etype,
                                                     agg, NEDGE / 2, NEDGE);
        gemm_mfma<<<(NENT + 127) / 128, 256, 0, stream>>>(
            agg, xin, lrel, Wp + WPLANE, Wp + 4 * WPLANE, hout, nullptr, 1.f / 3.f, NENT, 2);
        hipMemsetAsync(ds1, 0, 512 * sizeof(double), stream);
        colstats<<<(NENT + 499) / 500, 256, 0, stream>>>(hout, NENT, 500, ds1, ds2);
        finalize_stats<<<1, 256, 0, stream>>>(ds1, ds2, gg, bbeta, fsc, fsh, 200, (double)NENT);
        bn_act_200<<<4096, 256, 0, stream>>>(hout, fsc, fsh, (long)NENT * 50, 0);
        rel_mm<<<(40000 + 255) / 256, 256, 0, stream>>>(rin, wr, rout);
    };

    run_layer(init_embed, init_rel, w_in1, w_out1, w_loop1, w_rel1, lrel1, b1, gm1, be1, x1, r1v);
    run_layer(x1, r1v, w_in2, w_out2, w_loop2, w_rel2, lrel2, b2, gm2, be2, x2, r2v);

    // -------- ConvE head --------
    hipMemsetAsync(ds1, 0, 512 * sizeof(double), stream);
    build_stk<<<NB, 256, 0, stream>>>(x2, r2v, subj, relidx, stk, ds1, ds2);
    finalize_stats<<<1, 256, 0, stream>>>(ds1, ds2, bn0_g, bn0_b, fsc, fsh, 1,
                                          (double)((long)NB * 400));
    hipMemsetAsync(ds1, 0, 512 * sizeof(double), stream);
    conv_fwd<<<NB, 256, 0, stream>>>(stk, conv_w, conv_b, fsc, fsh, Ph, ds1, ds2);
    finalize_stats<<<1, 256, 0, stream>>>(ds1, ds2, bn1_g, bn1_b, fsc, fsh, 200,
                                          (double)((long)NB * 196));
    bn1_relu_f16<<<4096, 256, 0, stream>>>(Ph, fsc, fsh);
    pack_fcw<<<(int)(((long)208 * FLATSZ + 255) / 256), 256, 0, stream>>>(fc_w, fch);
    init_bias200<<<800, 256, 0, stream>>>(hfc, fc_b, (long)NB * 200);
    fc_gemm<<<dim3(8, 49), 256, 0, stream>>>(Ph, fch, hfc);
    hipMemsetAsync(ds1, 0, 512 * sizeof(double), stream);
    colstats<<<4, 256, 0, stream>>>(hfc, NB, 256, ds1, ds2);
    finalize_stats<<<1, 256, 0, stream>>>(ds1, ds2, bn2_g, bn2_b, fsc, fsh, 200, (double)NB);
    bn_act_200<<<200, 256, 0, stream>>>(hfc, fsc, fsh, (long)NB * 50, 1);
    score_mm<<<dim3(NB / 16, NB / 16), 256, 0, stream>>>(hfc, x2, obj, (float*)d_out);
}

// Round 4
// 1795.615 us; speedup vs baseline: 5.2717x; 3.8685x over previous
//
#include <hip/hip_runtime.h>

#define DIM 200
#define NENT 100000
#define NEDGE 1000000
#define EHALF 500000
#define NB 1024
#define NFILT 200
#define FLATSZ 39200

#define NDF ((size_t)NENT * DIM)      /* 20,000,000 floats per node matrix */
#define REGF ((size_t)20100000)       /* region stride in floats */
#define WPLANE (208 * 224)            /* one packed weight plane (3 segs each) */

typedef float floatx4 __attribute__((ext_vector_type(4)));
typedef short bf16x8 __attribute__((ext_vector_type(8)));
typedef _Float16 halfx8 __attribute__((ext_vector_type(8)));
typedef _Float16 halfx4 __attribute__((ext_vector_type(4)));

__device__ __forceinline__ void gAtomicAdd(float* p, float v) { unsafeAtomicAdd(p, v); }
__device__ __forceinline__ void gAtomicAdd(double* p, double v) { unsafeAtomicAdd(p, v); }

__device__ __forceinline__ short f2bf(float f) {
    union { float f; unsigned u; } v; v.f = f;
    unsigned r = v.u + 0x7fffu + ((v.u >> 16) & 1u);
    return (short)(r >> 16);
}
__device__ __forceinline__ float bf2f(short s) {
    union { float f; unsigned u; } v; v.u = ((unsigned)(unsigned short)s) << 16;
    return v.f;
}
__device__ __forceinline__ void split8(const floatx4& lo4, const floatx4& hi4,
                                       bf16x8& h, bf16x8& l) {
#pragma unroll
    for (int e = 0; e < 4; ++e) {
        short hh = f2bf(lo4[e]); h[e] = hh; l[e] = f2bf(lo4[e] - bf2f(hh));
        short hh2 = f2bf(hi4[e]); h[e + 4] = hh2; l[e + 4] = f2bf(hi4[e] - bf2f(hh2));
    }
}

// ---------------------------------------------------------------- CSR build (once per call)
__global__ __launch_bounds__(256) void edge_hist(
    const int* __restrict__ dst, int* __restrict__ hist)
{
    int stride = gridDim.x * blockDim.x;
    for (int e = blockIdx.x * 256 + threadIdx.x; e < NEDGE; e += stride)
        atomicAdd(&hist[dst[e]], 1);
}

// per-block inclusive scan of 256 hist entries -> incl (stored in offs), block total -> bsum
__global__ __launch_bounds__(256) void scan1(
    const int* __restrict__ hist, int* __restrict__ incl, int* __restrict__ bsum)
{
    __shared__ int sm[256];
    int i = blockIdx.x * 256 + threadIdx.x;
    int t = threadIdx.x;
    sm[t] = (i < NENT) ? hist[i] : 0;
    __syncthreads();
    for (int off = 1; off < 256; off <<= 1) {
        int v = (t >= off) ? sm[t - off] : 0;
        __syncthreads();
        sm[t] += v;
        __syncthreads();
    }
    if (i < NENT) incl[i] = sm[t];
    if (t == 255) bsum[blockIdx.x] = sm[255];
}

__global__ void scan2(int* bsum, int nb)
{
    if (threadIdx.x == 0) {
        int run = 0;
        for (int i = 0; i < nb; ++i) { int v = bsum[i]; bsum[i] = run; run += v; }
    }
}

// offs[i] = exclusive prefix; cursor[i] = same; offs[NENT] = NEDGE
__global__ __launch_bounds__(256) void scan3(
    const int* __restrict__ hist, int* __restrict__ offs,
    const int* __restrict__ bsum, int* __restrict__ cursor)
{
    int i = blockIdx.x * 256 + threadIdx.x;
    if (i < NENT) {
        int excl = offs[i] - hist[i] + bsum[blockIdx.x];
        offs[i] = excl;
        cursor[i] = excl;
    }
    if (i == 0) offs[NENT] = NEDGE;
}

// packed edge records sorted by dst: es=src, et=etype|(half<<16), en=enorm
__global__ __launch_bounds__(256) void edge_fill(
    const int* __restrict__ src, const int* __restrict__ dst,
    const int* __restrict__ etype, const float* __restrict__ enorm,
    int* __restrict__ cursor, int* __restrict__ es, int* __restrict__ et,
    float* __restrict__ en)
{
    int stride = gridDim.x * blockDim.x;
    for (int e = blockIdx.x * 256 + threadIdx.x; e < NEDGE; e += stride) {
        int pos = atomicAdd(&cursor[dst[e]], 1);
        es[pos] = src[e];
        et[pos] = etype[e] | ((e >= EHALF) ? 0x10000 : 0);
        en[pos] = enorm[e];
    }
}

// ---------------------------------------------------------------- gather (replaces atomic scatter)
// one wave per node; lanes 0..49 hold float4 slots of the 200-dim row
__global__ __launch_bounds__(256) void gather_nodes(
    const float* __restrict__ x, const float* __restrict__ r,
    const int* __restrict__ offs, const int* __restrict__ es,
    const int* __restrict__ et, const float* __restrict__ en,
    float* __restrict__ aggI, float* __restrict__ aggO)
{
    int node = blockIdx.x * 4 + (threadIdx.x >> 6);
    int lane = threadIdx.x & 63;
    if (node >= NENT) return;
    int beg = offs[node], end = offs[node + 1];
    bool act = lane < 50;
    const float4* xb = (const float4*)x;
    const float4* rb = (const float4*)r;
    float4 aI = make_float4(0.f, 0.f, 0.f, 0.f);
    float4 aO = make_float4(0.f, 0.f, 0.f, 0.f);
    for (int i = beg; i < end; ++i) {
        int s = es[i], tt = et[i];
        float w = en[i];
        float wI = (tt & 0x10000) ? 0.f : w;
        float wO = w - wI;
        if (act) {
            float4 xv = xb[(size_t)s * 50 + lane];
            float4 rv = rb[(size_t)(tt & 0xffff) * 50 + lane];
            float px = xv.x * rv.x, py = xv.y * rv.y, pz = xv.z * rv.z, pw = xv.w * rv.w;
            aI.x += px * wI; aI.y += py * wI; aI.z += pz * wI; aI.w += pw * wI;
            aO.x += px * wO; aO.y += py * wO; aO.z += pz * wO; aO.w += pw * wO;
        }
    }
    if (act) {
        ((float4*)aggI)[(size_t)node * 50 + lane] = aI;
        ((float4*)aggO)[(size_t)node * 50 + lane] = aO;
    }
}

// ---------------------------------------------------------------- weight packing
__global__ __launch_bounds__(256) void pack_w3(
    const float* __restrict__ w0, const float* __restrict__ w1,
    const float* __restrict__ w2, short* __restrict__ Wp)
{
    int i = blockIdx.x * 256 + threadIdx.x;
    if (i >= 3 * WPLANE) return;
    int seg = i / WPLANE, rem = i % WPLANE;
    int n = rem / 224, k = rem % 224;
    const float* W = (seg == 0) ? w0 : (seg == 1) ? w1 : w2;
    float v = (n < 200 && k < 200) ? W[k * 200 + n] : 0.f;
    short hi = f2bf(v);
    Wp[i] = hi;
    Wp[i + 3 * WPLANE] = f2bf(v - bf2f(hi));
}

__global__ __launch_bounds__(256) void pack_fcw(
    const float* __restrict__ W, _Float16* __restrict__ Wt)
{
    long i = (long)blockIdx.x * 256 + threadIdx.x;
    if (i >= (long)208 * FLATSZ) return;
    int n = (int)(i / FLATSZ);
    Wt[i] = (n < 200) ? (_Float16)W[i] : (_Float16)0.f;
}

// ---------------------------------------------------------------- split-bf16 MFMA GEMM, 3 segments
// C[M,200] = alpha*(A0@W0 + A1@W1 + (A2*scale2)@W2) + bias
// NOTE: C may alias A0 (in-place): each block writes only rows it alone read.
__global__ __launch_bounds__(256) void gemm_mfma(
    const float* A0, const float* A1, const float* A2,
    const float* __restrict__ scale2, const short* __restrict__ WpH,
    const short* __restrict__ WpL, float* C, const float* __restrict__ bias,
    float alpha, int M)
{
    __shared__ short BsH[208 * 40];
    __shared__ short BsL[208 * 40];
    int t = threadIdx.x;
    int lane = t & 63, wave = t >> 6;
    int col16 = lane & 15, quad = lane >> 4;
    int row_base = blockIdx.x * 128 + wave * 32;
    floatx4 acc[13][2];
#pragma unroll
    for (int nf = 0; nf < 13; ++nf) { acc[nf][0] = (floatx4)0.f; acc[nf][1] = (floatx4)0.f; }
    int r0 = row_base + col16, r1 = row_base + 16 + col16;
    int r0c = min(r0, M - 1), r1c = min(r1, M - 1);

    for (int seg = 0; seg < 3; ++seg) {
        const float* Ap = (seg == 0) ? A0 : (seg == 1) ? A1 : A2;
        const float* sc = (seg == 2) ? scale2 : nullptr;
        const short* WH = WpH + seg * WPLANE;
        const short* WL = WpL + seg * WPLANE;
        for (int c = 0; c < 7; ++c) {
            int k0 = c * 32;
            for (int i = t; i < 208 * 4; i += 256) {
                int n = i >> 2, part = i & 3;
                *(bf16x8*)&BsH[n * 40 + part * 8] = *(const bf16x8*)&WH[n * 224 + k0 + part * 8];
                *(bf16x8*)&BsL[n * 40 + part * 8] = *(const bf16x8*)&WL[n * 224 + k0 + part * 8];
            }
            __syncthreads();
            int koff = k0 + quad * 8;
            bf16x8 a0h, a0l, a1h, a1l;
            if (koff < 200) {
                floatx4 lo0 = *(const floatx4*)&Ap[(size_t)r0c * 200 + koff];
                floatx4 hi0 = *(const floatx4*)&Ap[(size_t)r0c * 200 + koff + 4];
                floatx4 lo1 = *(const floatx4*)&Ap[(size_t)r1c * 200 + koff];
                floatx4 hi1 = *(const floatx4*)&Ap[(size_t)r1c * 200 + koff + 4];
                if (sc) {
                    floatx4 slo = *(const floatx4*)&sc[koff];
                    floatx4 shi = *(const floatx4*)&sc[koff + 4];
                    lo0 *= slo; hi0 *= shi; lo1 *= slo; hi1 *= shi;
                }
                split8(lo0, hi0, a0h, a0l);
                split8(lo1, hi1, a1h, a1l);
            } else {
                a0h = (bf16x8)0; a0l = (bf16x8)0; a1h = (bf16x8)0; a1l = (bf16x8)0;
            }
#pragma unroll
            for (int nf = 0; nf < 13; ++nf) {
                bf16x8 bh = *(const bf16x8*)&BsH[(nf * 16 + col16) * 40 + quad * 8];
                bf16x8 bl = *(const bf16x8*)&BsL[(nf * 16 + col16) * 40 + quad * 8];
                acc[nf][0] = __builtin_amdgcn_mfma_f32_16x16x32_bf16(a0h, bh, acc[nf][0], 0, 0, 0);
                acc[nf][0] = __builtin_amdgcn_mfma_f32_16x16x32_bf16(a0h, bl, acc[nf][0], 0, 0, 0);
                acc[nf][0] = __builtin_amdgcn_mfma_f32_16x16x32_bf16(a0l, bh, acc[nf][0], 0, 0, 0);
                acc[nf][1] = __builtin_amdgcn_mfma_f32_16x16x32_bf16(a1h, bh, acc[nf][1], 0, 0, 0);
                acc[nf][1] = __builtin_amdgcn_mfma_f32_16x16x32_bf16(a1h, bl, acc[nf][1], 0, 0, 0);
                acc[nf][1] = __builtin_amdgcn_mfma_f32_16x16x32_bf16(a1l, bh, acc[nf][1], 0, 0, 0);
            }
            __syncthreads();
        }
    }
#pragma unroll
    for (int nf = 0; nf < 13; ++nf) {
        int colg = nf * 16 + col16;
        if (colg >= 200) continue;
        float bv = bias[colg];
#pragma unroll
        for (int h = 0; h < 2; ++h) {
            int rbase = row_base + h * 16 + quad * 4;
#pragma unroll
            for (int j = 0; j < 4; ++j) {
                int rr = rbase + j;
                if (rr < M) C[(size_t)rr * 200 + colg] = acc[nf][h][j] * alpha + bv;
            }
        }
    }
}

// ---------------------------------------------------------------- fc MFMA GEMM (fp16), split-K, atomic accumulate
__global__ __launch_bounds__(256) void fc_gemm(
    const _Float16* __restrict__ Ph, const _Float16* __restrict__ Wt,
    float* __restrict__ C)
{
    __shared__ _Float16 Bs[208 * 40];
    int t = threadIdx.x;
    int lane = t & 63, wave = t >> 6;
    int col16 = lane & 15, quad = lane >> 4;
    int row_base = blockIdx.x * 128 + wave * 32;
    int c0 = blockIdx.y * 25;
    floatx4 acc[13][2];
#pragma unroll
    for (int nf = 0; nf < 13; ++nf) { acc[nf][0] = (floatx4)0.f; acc[nf][1] = (floatx4)0.f; }
    int r0 = row_base + col16, r1 = row_base + 16 + col16;

    for (int c = c0; c < c0 + 25; ++c) {
        int k0 = c * 32;
        for (int i = t; i < 208 * 4; i += 256) {
            int n = i >> 2, part = i & 3;
            *(halfx8*)&Bs[n * 40 + part * 8] =
                *(const halfx8*)&Wt[(size_t)n * FLATSZ + k0 + part * 8];
        }
        __syncthreads();
        int koff = k0 + quad * 8;
        halfx8 a0 = *(const halfx8*)&Ph[(size_t)r0 * FLATSZ + koff];
        halfx8 a1 = *(const halfx8*)&Ph[(size_t)r1 * FLATSZ + koff];
#pragma unroll
        for (int nf = 0; nf < 13; ++nf) {
            halfx8 b = *(const halfx8*)&Bs[(nf * 16 + col16) * 40 + quad * 8];
            acc[nf][0] = __builtin_amdgcn_mfma_f32_16x16x32_f16(a0, b, acc[nf][0], 0, 0, 0);
            acc[nf][1] = __builtin_amdgcn_mfma_f32_16x16x32_f16(a1, b, acc[nf][1], 0, 0, 0);
        }
        __syncthreads();
    }
#pragma unroll
    for (int nf = 0; nf < 13; ++nf) {
        int colg = nf * 16 + col16;
        if (colg >= 200) continue;
#pragma unroll
        for (int h = 0; h < 2; ++h) {
            int rbase = row_base + h * 16 + quad * 4;
#pragma unroll
            for (int j = 0; j < 4; ++j)
                gAtomicAdd(&C[(size_t)(rbase + j) * 200 + colg], acc[nf][h][j]);
        }
    }
}

// ---------------------------------------------------------------- stats / bn
__global__ __launch_bounds__(256) void colstats(
    const float* __restrict__ X, int M, int rpb,
    double* __restrict__ s1, double* __restrict__ s2)
{
    int c = threadIdx.x;
    if (c >= 200) return;
    int r0 = blockIdx.x * rpb;
    int r1 = min(r0 + rpb, M);
    float sum = 0.f, sq = 0.f;
    for (int rr = r0; rr < r1; ++rr) {
        float v = X[(size_t)rr * 200 + c];
        sum += v; sq += v * v;
    }
    gAtomicAdd(&s1[c], (double)sum);
    gAtomicAdd(&s2[c], (double)sq);
}

__global__ void finalize_stats(const double* __restrict__ s1, const double* __restrict__ s2,
                               const float* __restrict__ g, const float* __restrict__ bb,
                               float* __restrict__ sc, float* __restrict__ sh,
                               int ncols, double count)
{
    int c = threadIdx.x;
    if (c >= ncols) return;
    double m = s1[c] / count;
    double v = s2[c] / count - m * m;
    double scd = (double)g[c] / sqrt(v + 1e-5);
    sc[c] = (float)scd;
    sh[c] = (float)((double)bb[c] - m * scd);
}

__global__ __launch_bounds__(256) void bn_act_200(
    float* __restrict__ X, const float* __restrict__ sc, const float* __restrict__ sh,
    long n4, int act)
{
    long stride = (long)gridDim.x * blockDim.x;
    for (long i = (long)blockIdx.x * blockDim.x + threadIdx.x; i < n4; i += stride) {
        int c4 = (int)(i % 50) * 4;
        float4 v = ((const float4*)X)[i];
        float a0 = v.x * sc[c4 + 0] + sh[c4 + 0];
        float a1 = v.y * sc[c4 + 1] + sh[c4 + 1];
        float a2 = v.z * sc[c4 + 2] + sh[c4 + 2];
        float a3 = v.w * sc[c4 + 3] + sh[c4 + 3];
        if (act == 0) { a0 = tanhf(a0); a1 = tanhf(a1); a2 = tanhf(a2); a3 = tanhf(a3); }
        else { a0 = fmaxf(a0, 0.f); a1 = fmaxf(a1, 0.f); a2 = fmaxf(a2, 0.f); a3 = fmaxf(a3, 0.f); }
        ((float4*)X)[i] = make_float4(a0, a1, a2, a3);
    }
}

__global__ __launch_bounds__(256) void init_bias200(
    float* __restrict__ C, const float* __restrict__ b, long n)
{
    long stride = (long)gridDim.x * blockDim.x;
    for (long i = (long)blockIdx.x * blockDim.x + threadIdx.x; i < n; i += stride)
        C[i] = b[(int)(i % 200)];
}

__global__ __launch_bounds__(256) void rel_mm(
    const float* __restrict__ R, const float* __restrict__ W, float* __restrict__ O)
{
    int idx = blockIdx.x * blockDim.x + threadIdx.x;
    if (idx >= 200 * 200) return;
    int row = idx / 200, col = idx - row * 200;
    float acc = 0.f;
    for (int k = 0; k < 200; ++k) acc = fmaf(R[row * 200 + k], W[k * 200 + col], acc);
    O[idx] = acc;
}

__global__ __launch_bounds__(256) void build_stk(
    const float* __restrict__ x2, const float* __restrict__ r2,
    const int* __restrict__ subj, const int* __restrict__ ridx,
    float* __restrict__ stk, double* __restrict__ s1, double* __restrict__ s2)
{
    int b = blockIdx.x, t = threadIdx.x;
    const float* se = x2 + (size_t)subj[b] * DIM;
    const float* re = r2 + (size_t)ridx[b] * DIM;
    float sum = 0.f, sq = 0.f;
    for (int i = t; i < 400; i += 256) {
        float v = (i < 200) ? se[i] : re[i - 200];
        stk[(size_t)b * 400 + i] = v;
        sum += v; sq += v * v;
    }
    for (int off = 32; off > 0; off >>= 1) {
        sum += __shfl_down(sum, off);
        sq  += __shfl_down(sq, off);
    }
    if ((t & 63) == 0) { gAtomicAdd(&s1[0], (double)sum); gAtomicAdd(&s2[0], (double)sq); }
}

__global__ __launch_bounds__(256) void conv_fwd(
    const float* __restrict__ stk, const float* __restrict__ conv_w,
    const float* __restrict__ conv_b, const float* __restrict__ sc0,
    const float* __restrict__ sh0, _Float16* __restrict__ Ph,
    double* __restrict__ s1, double* __restrict__ s2)
{
    __shared__ float img[400];
    __shared__ float wsm[9800];
    __shared__ float bsm[200];
    __shared__ float fsum[200];
    __shared__ float fsq[200];
    int b = blockIdx.x, t = threadIdx.x;
    float scale0 = sc0[0], shift0 = sh0[0];
    if (t < 200) { fsum[t] = 0.f; fsq[t] = 0.f; bsm[t] = conv_b[t]; }
    for (int i = t; i < 400; i += 256) img[i] = stk[(size_t)b * 400 + i] * scale0 + shift0;
    for (int i = t; i < 9800; i += 256) wsm[i] = conv_w[i];
    __syncthreads();
    for (int fy = t; fy < 2800; fy += 256) {
        int f = fy / 14, y = fy - (fy / 14) * 14;
        const float* wf = &wsm[f * 49];
        float acc[14];
        float bias = bsm[f];
#pragma unroll
        for (int xx = 0; xx < 14; ++xx) acc[xx] = bias;
#pragma unroll
        for (int i = 0; i < 7; ++i) {
            const float* rowp = &img[(y + i) * 20];
            float rv[20];
#pragma unroll
            for (int c = 0; c < 20; ++c) rv[c] = rowp[c];
#pragma unroll
            for (int j = 0; j < 7; ++j) {
                float wv = wf[i * 7 + j];
#pragma unroll
                for (int xx = 0; xx < 14; ++xx) acc[xx] = fmaf(rv[xx + j], wv, acc[xx]);
            }
        }
        float ls = 0.f, lq = 0.f;
        _Float16* pp = Ph + (size_t)b * FLATSZ + (size_t)f * 196 + y * 14;
#pragma unroll
        for (int xx = 0; xx < 14; ++xx) {
            float v = acc[xx];
            pp[xx] = (_Float16)v;
            ls += v; lq += v * v;
        }
        atomicAdd(&fsum[f], ls);
        atomicAdd(&fsq[f], lq);
    }
    __syncthreads();
    if (t < 200) {
        gAtomicAdd(&s1[t], (double)fsum[t]);
        gAtomicAdd(&s2[t], (double)fsq[t]);
    }
}

__global__ __launch_bounds__(256) void bn1_relu_f16(
    _Float16* __restrict__ Ph, const float* __restrict__ sc, const float* __restrict__ sh)
{
    long n4 = (long)NB * (FLATSZ / 4);
    long stride = (long)gridDim.x * blockDim.x;
    for (long i = (long)blockIdx.x * blockDim.x + threadIdx.x; i < n4; i += stride) {
        int k4 = (int)(i % (FLATSZ / 4));
        int f = k4 / 49;
        float s = sc[f], h = sh[f];
        halfx4 v = ((const halfx4*)Ph)[i];
#pragma unroll
        for (int e = 0; e < 4; ++e) {
            float x = (float)v[e];
            x = fmaxf(x * s + h, 0.f);
            v[e] = (_Float16)x;
        }
        ((halfx4*)Ph)[i] = v;
    }
}

__global__ __launch_bounds__(256) void score_mm(
    const float* __restrict__ Hn, const float* __restrict__ x2,
    const int* __restrict__ obj, float* __restrict__ out)
{
    __shared__ float Asm[16][17];
    __shared__ float Bsm[16][17];
    int tx = threadIdx.x & 15, ty = threadIdx.x >> 4;
    int row = blockIdx.y * 16 + ty;
    int col = blockIdx.x * 16 + tx;
    int oj = obj[blockIdx.x * 16 + ty];
    float acc = 0.f;
    for (int k0 = 0; k0 < 200; k0 += 16) {
        int k = k0 + tx;
        Asm[ty][tx] = (k < 200) ? Hn[(size_t)row * 200 + k] : 0.f;
        Bsm[ty][tx] = (k < 200) ? x2[(size_t)oj * 200 + k] : 0.f;
        __syncthreads();
#pragma unroll
        for (int kk = 0; kk < 16; ++kk) acc = fmaf(Asm[ty][kk], Bsm[tx][kk], acc);
        __syncthreads();
    }
    out[(size_t)row * NB + col] = 1.f / (1.f + expf(-acc));
}

// ---------------------------------------------------------------- driver
extern "C" void kernel_launch(void* const* d_in, const int* in_sizes, int n_in,
                              void* d_out, int out_size, void* d_ws, size_t ws_size,
                              hipStream_t stream)
{
    (void)in_sizes; (void)n_in; (void)out_size;
    const float* init_embed = (const float*)d_in[0];
    const float* init_rel   = (const float*)d_in[1];
    const float* edge_norm  = (const float*)d_in[2];
    const float* w_in1  = (const float*)d_in[3];
    const float* w_out1 = (const float*)d_in[4];
    const float* w_loop1= (const float*)d_in[5];
    const float* w_rel1 = (const float*)d_in[6];
    const float* lrel1  = (const float*)d_in[7];
    const float* b1     = (const float*)d_in[8];
    const float* gm1    = (const float*)d_in[9];
    const float* be1    = (const float*)d_in[10];
    const float* w_in2  = (const float*)d_in[11];
    const float* w_out2 = (const float*)d_in[12];
    const float* w_loop2= (const float*)d_in[13];
    const float* w_rel2 = (const float*)d_in[14];
    const float* lrel2  = (const float*)d_in[15];
    const float* b2     = (const float*)d_in[16];
    const float* gm2    = (const float*)d_in[17];
    const float* be2    = (const float*)d_in[18];
    const float* conv_w = (const float*)d_in[19];
    const float* conv_b = (const float*)d_in[20];
    const float* fc_w   = (const float*)d_in[21];
    const float* fc_b   = (const float*)d_in[22];
    const float* bn0_g  = (const float*)d_in[23];
    const float* bn0_b  = (const float*)d_in[24];
    const float* bn1_g  = (const float*)d_in[25];
    const float* bn1_b  = (const float*)d_in[26];
    const float* bn2_g  = (const float*)d_in[27];
    const float* bn2_b  = (const float*)d_in[28];
    const int* subj   = (const int*)d_in[29];
    const int* relidx = (const int*)d_in[30];
    const int* obj    = (const int*)d_in[31];
    const int* src    = (const int*)d_in[32];
    const int* dst    = (const int*)d_in[33];
    const int* etype  = (const int*)d_in[34];

    float* ws = (float*)d_ws;
    float* R0 = ws;                        // x1, later Ph (fp16 conv out)
    float* R1 = ws + REGF;                 // aggI, layer2 C in-place -> x2
    float* R2 = ws + 2 * REGF;             // aggO, later fch (fp16 fc weights)
    float* p = ws + 3 * REGF;              // tail
    float* r1v = p;            p += 40000;
    float* r2v = p;            p += 40000;
    float* stk = p;            p += 409600;
    float* hfc = p;            p += 204800;
    float* fsc = p;            p += 256;
    float* fsh = p;            p += 256;
    double* ds1 = (double*)p;  p += 512;   // ds1
    double* ds2 = ds1 + 256;               // second half of those 512 floats... (see below)
    // NOTE: ds1 occupies 256 doubles = 512 floats; ds2 the next 256 doubles:
    p += 512;                              // ds2 (another 512 floats)
    short* Wp = (short*)p;     p += (6 * WPLANE) / 2;
    int* hist = (int*)p;       p += NENT;
    int* offs = (int*)p;       p += NENT + 1;
    int* cursor = (int*)p;     p += NENT;
    int* bsum = (int*)p;       p += 512;
    int* es = (int*)p;         p += NEDGE;
    int* et = (int*)p;         p += NEDGE;
    float* en = p;             p += NEDGE;

    float* x1 = R0;
    float* aggI = R1;
    float* aggO = R2;
    _Float16* Ph  = (_Float16*)R0;
    _Float16* fch = (_Float16*)R2;

    const size_t NEED = (size_t)(p - ws) * sizeof(float);
    if (ws_size < NEED) return;

    const int NBLK = (NENT + 255) / 256;   // 391

    // -------- CSR build (dst is identical for both layers) --------
    hipMemsetAsync(hist, 0, NENT * sizeof(int), stream);
    edge_hist<<<1024, 256, 0, stream>>>(dst, hist);
    scan1<<<NBLK, 256, 0, stream>>>(hist, offs, bsum);
    scan2<<<1, 64, 0, stream>>>(bsum, NBLK);
    scan3<<<NBLK, 256, 0, stream>>>(hist, offs, bsum, cursor);
    edge_fill<<<1024, 256, 0, stream>>>(src, dst, etype, edge_norm, cursor, es, et, en);

    // -------- one CompGCN layer --------
    auto run_layer = [&](const float* xin, const float* rin,
                         const float* wi, const float* wo, const float* wl,
                         const float* wr, const float* lrel, const float* bias,
                         const float* gg, const float* bbeta,
                         float* hout, float* rout) {
        pack_w3<<<(3 * WPLANE + 255) / 256, 256, 0, stream>>>(wi, wo, wl, Wp);
        gather_nodes<<<(NENT + 3) / 4, 256, 0, stream>>>(xin, rin, offs, es, et, en,
                                                         aggI, aggO);
        gemm_mfma<<<(NENT + 127) / 128, 256, 0, stream>>>(
            aggI, aggO, xin, lrel, Wp, Wp + 3 * WPLANE, hout, bias, 1.f / 3.f, NENT);
        hipMemsetAsync(ds1, 0, 512 * sizeof(double), stream);
        colstats<<<(NENT + 499) / 500, 256, 0, stream>>>(hout, NENT, 500, ds1, ds2);
        finalize_stats<<<1, 256, 0, stream>>>(ds1, ds2, gg, bbeta, fsc, fsh, 200, (double)NENT);
        bn_act_200<<<4096, 256, 0, stream>>>(hout, fsc, fsh, (long)NENT * 50, 0);
        rel_mm<<<(40000 + 255) / 256, 256, 0, stream>>>(rin, wr, rout);
    };

    run_layer(init_embed, init_rel, w_in1, w_out1, w_loop1, w_rel1, lrel1, b1, gm1, be1,
              x1, r1v);
    // layer 2: C written in-place over aggI (R1); x1 (R0) is the A2 input
    run_layer(x1, r1v, w_in2, w_out2, w_loop2, w_rel2, lrel2, b2, gm2, be2,
              aggI, r2v);
    float* x2 = aggI;                      // R1 holds final node embeddings

    // -------- ConvE head --------
    hipMemsetAsync(ds1, 0, 512 * sizeof(double), stream);
    build_stk<<<NB, 256, 0, stream>>>(x2, r2v, subj, relidx, stk, ds1, ds2);
    finalize_stats<<<1, 256, 0, stream>>>(ds1, ds2, bn0_g, bn0_b, fsc, fsh, 1,
                                          (double)((long)NB * 400));
    hipMemsetAsync(ds1, 0, 512 * sizeof(double), stream);
    conv_fwd<<<NB, 256, 0, stream>>>(stk, conv_w, conv_b, fsc, fsh, Ph, ds1, ds2);
    finalize_stats<<<1, 256, 0, stream>>>(ds1, ds2, bn1_g, bn1_b, fsc, fsh, 200,
                                          (double)((long)NB * 196));
    bn1_relu_f16<<<4096, 256, 0, stream>>>(Ph, fsc, fsh);
    pack_fcw<<<(int)(((long)208 * FLATSZ + 255) / 256), 256, 0, stream>>>(fc_w, fch);
    init_bias200<<<800, 256, 0, stream>>>(hfc, fc_b, (long)NB * 200);
    fc_gemm<<<dim3(8, 49), 256, 0, stream>>>(Ph, fch, hfc);
    hipMemsetAsync(ds1, 0, 512 * sizeof(double), stream);
    colstats<<<4, 256, 0, stream>>>(hfc, NB, 256, ds1, ds2);
    finalize_stats<<<1, 256, 0, stream>>>(ds1, ds2, bn2_g, bn2_b, fsc, fsh, 200, (double)NB);
    bn_act_200<<<200, 256, 0, stream>>>(hfc, fsc, fsh, (long)NB * 50, 1);
    score_mm<<<dim3(NB / 16, NB / 16), 256, 0, stream>>>(hfc, x2, obj, (float*)d_out);
}

// Round 6
// 1520.674 us; speedup vs baseline: 6.2248x; 1.1808x over previous
//
#include <hip/hip_runtime.h>

#define DIM 200
#define NENT 100000
#define NEDGE 1000000
#define EHALF 500000
#define NB 1024
#define NFILT 200
#define FLATSZ 39200

#define NDF ((size_t)NENT * DIM)
#define REGF ((size_t)20100000)
#define WPLANE (208 * 224)

typedef float floatx4 __attribute__((ext_vector_type(4)));
typedef short bf16x8 __attribute__((ext_vector_type(8)));
typedef _Float16 halfx8 __attribute__((ext_vector_type(8)));
typedef _Float16 halfx4 __attribute__((ext_vector_type(4)));

__device__ __forceinline__ void gAtomicAdd(float* p, float v) { unsafeAtomicAdd(p, v); }
__device__ __forceinline__ void gAtomicAdd(double* p, double v) { unsafeAtomicAdd(p, v); }

__device__ __forceinline__ short f2bf(float f) {
    union { float f; unsigned u; } v; v.f = f;
    unsigned r = v.u + 0x7fffu + ((v.u >> 16) & 1u);
    return (short)(r >> 16);
}
__device__ __forceinline__ float bf2f(short s) {
    union { float f; unsigned u; } v; v.u = ((unsigned)(unsigned short)s) << 16;
    return v.f;
}
__device__ __forceinline__ void split8(const floatx4& lo4, const floatx4& hi4,
                                       bf16x8& h, bf16x8& l) {
#pragma unroll
    for (int e = 0; e < 4; ++e) {
        short hh = f2bf(lo4[e]); h[e] = hh; l[e] = f2bf(lo4[e] - bf2f(hh));
        short hh2 = f2bf(hi4[e]); h[e + 4] = hh2; l[e + 4] = f2bf(hi4[e] - bf2f(hh2));
    }
}

// ---------------------------------------------------------------- CSR build
__global__ __launch_bounds__(256) void edge_hist(
    const int* __restrict__ dst, int* __restrict__ hist)
{
    int stride = gridDim.x * blockDim.x;
    for (int e = blockIdx.x * 256 + threadIdx.x; e < NEDGE; e += stride)
        atomicAdd(&hist[dst[e]], 1);
}

__global__ __launch_bounds__(256) void scan1(
    const int* __restrict__ hist, int* __restrict__ incl, int* __restrict__ bsum)
{
    __shared__ int sm[256];
    int i = blockIdx.x * 256 + threadIdx.x;
    int t = threadIdx.x;
    sm[t] = (i < NENT) ? hist[i] : 0;
    __syncthreads();
    for (int off = 1; off < 256; off <<= 1) {
        int v = (t >= off) ? sm[t - off] : 0;
        __syncthreads();
        sm[t] += v;
        __syncthreads();
    }
    if (i < NENT) incl[i] = sm[t];
    if (t == 255) bsum[blockIdx.x] = sm[255];
}

__global__ void scan2(int* bsum, int nb)
{
    if (threadIdx.x == 0) {
        int run = 0;
        for (int i = 0; i < nb; ++i) { int v = bsum[i]; bsum[i] = run; run += v; }
    }
}

__global__ __launch_bounds__(256) void scan3(
    const int* __restrict__ hist, int* __restrict__ offs,
    const int* __restrict__ bsum, int* __restrict__ cursor)
{
    int i = blockIdx.x * 256 + threadIdx.x;
    if (i < NENT) {
        int excl = offs[i] - hist[i] + bsum[blockIdx.x];
        offs[i] = excl;
        cursor[i] = excl;
    }
    if (i == 0) offs[NENT] = NEDGE;
}

__global__ __launch_bounds__(256) void edge_fill(
    const int* __restrict__ src, const int* __restrict__ dst,
    const int* __restrict__ etype, const float* __restrict__ enorm,
    int* __restrict__ cursor, int* __restrict__ es, int* __restrict__ et,
    float* __restrict__ en)
{
    int stride = gridDim.x * blockDim.x;
    for (int e = blockIdx.x * 256 + threadIdx.x; e < NEDGE; e += stride) {
        int pos = atomicAdd(&cursor[dst[e]], 1);
        es[pos] = src[e];
        et[pos] = etype[e] | ((e >= EHALF) ? 0x10000 : 0);
        en[pos] = enorm[e];
    }
}

// ---------------------------------------------------------------- gather
__global__ __launch_bounds__(256) void gather_nodes(
    const float* __restrict__ x, const float* __restrict__ r,
    const int* __restrict__ offs, const int* __restrict__ es,
    const int* __restrict__ et, const float* __restrict__ en,
    float* __restrict__ aggI, float* __restrict__ aggO)
{
    int node = blockIdx.x * 4 + (threadIdx.x >> 6);
    int lane = threadIdx.x & 63;
    if (node >= NENT) return;
    int beg = offs[node], end = offs[node + 1];
    bool act = lane < 50;
    const float4* xb = (const float4*)x;
    const float4* rb = (const float4*)r;
    float4 aI = make_float4(0.f, 0.f, 0.f, 0.f);
    float4 aO = make_float4(0.f, 0.f, 0.f, 0.f);
    for (int i = beg; i < end; ++i) {
        int s = es[i], tt = et[i];
        float w = en[i];
        float wI = (tt & 0x10000) ? 0.f : w;
        float wO = w - wI;
        if (act) {
            float4 xv = xb[(size_t)s * 50 + lane];
            float4 rv = rb[(size_t)(tt & 0xffff) * 50 + lane];
            float px = xv.x * rv.x, py = xv.y * rv.y, pz = xv.z * rv.z, pw = xv.w * rv.w;
            aI.x += px * wI; aI.y += py * wI; aI.z += pz * wI; aI.w += pw * wI;
            aO.x += px * wO; aO.y += py * wO; aO.z += pz * wO; aO.w += pw * wO;
        }
    }
    if (act) {
        ((float4*)aggI)[(size_t)node * 50 + lane] = aI;
        ((float4*)aggO)[(size_t)node * 50 + lane] = aO;
    }
}

// ---------------------------------------------------------------- weight packing
__global__ __launch_bounds__(256) void pack_w3(
    const float* __restrict__ w0, const float* __restrict__ w1,
    const float* __restrict__ w2, short* __restrict__ Wp)
{
    int i = blockIdx.x * 256 + threadIdx.x;
    if (i >= 3 * WPLANE) return;
    int seg = i / WPLANE, rem = i % WPLANE;
    int n = rem / 224, k = rem % 224;
    const float* W = (seg == 0) ? w0 : (seg == 1) ? w1 : w2;
    float v = (n < 200 && k < 200) ? W[k * 200 + n] : 0.f;
    short hi = f2bf(v);
    Wp[i] = hi;
    Wp[i + 3 * WPLANE] = f2bf(v - bf2f(hi));
}

__global__ __launch_bounds__(256) void pack_fcw(
    const float* __restrict__ W, _Float16* __restrict__ Wt)
{
    long i = (long)blockIdx.x * 256 + threadIdx.x;
    if (i >= (long)208 * FLATSZ) return;
    int n = (int)(i / FLATSZ);
    Wt[i] = (n < 200) ? (_Float16)W[i] : (_Float16)0.f;
}

// ---------------------------------------------------------------- split-bf16 MFMA GEMM, 3 segments
// C[M,200] = alpha*(A0@W0 + A1@W1 + (A2*scale2)@W2) + bias, fused col stats.
// C may alias A0 (each block writes only rows it alone read).
__global__ __launch_bounds__(256) void gemm_mfma(
    const float* A0, const float* A1, const float* A2,
    const float* __restrict__ scale2, const short* __restrict__ WpH,
    const short* __restrict__ WpL, float* C, const float* __restrict__ bias,
    float alpha, int M, double* __restrict__ s1, double* __restrict__ s2)
{
    __shared__ short BsH[208 * 40];
    __shared__ short BsL[208 * 40];
    __shared__ float fsum[208];
    __shared__ float fsq[208];
    int t = threadIdx.x;
    int lane = t & 63, wave = t >> 6;
    int col16 = lane & 15, quad = lane >> 4;
    int row_base = blockIdx.x * 128 + wave * 32;
    if (t < 208) { fsum[t] = 0.f; fsq[t] = 0.f; }
    floatx4 acc[13][2];
#pragma unroll
    for (int nf = 0; nf < 13; ++nf) { acc[nf][0] = (floatx4)0.f; acc[nf][1] = (floatx4)0.f; }
    int r0 = row_base + col16, r1 = row_base + 16 + col16;
    int r0c = min(r0, M - 1), r1c = min(r1, M - 1);

    for (int seg = 0; seg < 3; ++seg) {
        const float* Ap = (seg == 0) ? A0 : (seg == 1) ? A1 : A2;
        const float* sc = (seg == 2) ? scale2 : nullptr;
        const short* WH = WpH + seg * WPLANE;
        const short* WL = WpL + seg * WPLANE;
        for (int c = 0; c < 7; ++c) {
            int k0 = c * 32;
            for (int i = t; i < 208 * 4; i += 256) {
                int n = i >> 2, part = i & 3;
                *(bf16x8*)&BsH[n * 40 + part * 8] = *(const bf16x8*)&WH[n * 224 + k0 + part * 8];
                *(bf16x8*)&BsL[n * 40 + part * 8] = *(const bf16x8*)&WL[n * 224 + k0 + part * 8];
            }
            __syncthreads();
            int koff = k0 + quad * 8;
            bf16x8 a0h, a0l, a1h, a1l;
            if (koff < 200) {
                floatx4 lo0 = *(const floatx4*)&Ap[(size_t)r0c * 200 + koff];
                floatx4 hi0 = *(const floatx4*)&Ap[(size_t)r0c * 200 + koff + 4];
                floatx4 lo1 = *(const floatx4*)&Ap[(size_t)r1c * 200 + koff];
                floatx4 hi1 = *(const floatx4*)&Ap[(size_t)r1c * 200 + koff + 4];
                if (sc) {
                    floatx4 slo = *(const floatx4*)&sc[koff];
                    floatx4 shi = *(const floatx4*)&sc[koff + 4];
                    lo0 *= slo; hi0 *= shi; lo1 *= slo; hi1 *= shi;
                }
                split8(lo0, hi0, a0h, a0l);
                split8(lo1, hi1, a1h, a1l);
            } else {
                a0h = (bf16x8)0; a0l = (bf16x8)0; a1h = (bf16x8)0; a1l = (bf16x8)0;
            }
#pragma unroll
            for (int nf = 0; nf < 13; ++nf) {
                bf16x8 bh = *(const bf16x8*)&BsH[(nf * 16 + col16) * 40 + quad * 8];
                bf16x8 bl = *(const bf16x8*)&BsL[(nf * 16 + col16) * 40 + quad * 8];
                acc[nf][0] = __builtin_amdgcn_mfma_f32_16x16x32_bf16(a0h, bh, acc[nf][0], 0, 0, 0);
                acc[nf][0] = __builtin_amdgcn_mfma_f32_16x16x32_bf16(a0h, bl, acc[nf][0], 0, 0, 0);
                acc[nf][0] = __builtin_amdgcn_mfma_f32_16x16x32_bf16(a0l, bh, acc[nf][0], 0, 0, 0);
                acc[nf][1] = __builtin_amdgcn_mfma_f32_16x16x32_bf16(a1h, bh, acc[nf][1], 0, 0, 0);
                acc[nf][1] = __builtin_amdgcn_mfma_f32_16x16x32_bf16(a1h, bl, acc[nf][1], 0, 0, 0);
                acc[nf][1] = __builtin_amdgcn_mfma_f32_16x16x32_bf16(a1l, bh, acc[nf][1], 0, 0, 0);
            }
            __syncthreads();
        }
    }
#pragma unroll
    for (int nf = 0; nf < 13; ++nf) {
        int colg = nf * 16 + col16;
        if (colg >= 200) continue;
        float bv = bias[colg];
        float ls = 0.f, lq = 0.f;
#pragma unroll
        for (int h = 0; h < 2; ++h) {
            int rbase = row_base + h * 16 + quad * 4;
#pragma unroll
            for (int j = 0; j < 4; ++j) {
                int rr = rbase + j;
                if (rr < M) {
                    float v = acc[nf][h][j] * alpha + bv;
                    C[(size_t)rr * 200 + colg] = v;
                    ls += v; lq += v * v;
                }
            }
        }
        atomicAdd(&fsum[colg], ls);
        atomicAdd(&fsq[colg], lq);
    }
    __syncthreads();
    if (t < 200) {
        gAtomicAdd(&s1[t], (double)fsum[t]);
        gAtomicAdd(&s2[t], (double)fsq[t]);
    }
}

// ---------------------------------------------------------------- fc MFMA GEMM (fp16), split-K
__global__ __launch_bounds__(256) void fc_gemm(
    const _Float16* __restrict__ Ph, const _Float16* __restrict__ Wt,
    float* __restrict__ C)
{
    __shared__ _Float16 Bs[208 * 40];
    int t = threadIdx.x;
    int lane = t & 63, wave = t >> 6;
    int col16 = lane & 15, quad = lane >> 4;
    int row_base = blockIdx.x * 128 + wave * 32;
    int c0 = blockIdx.y * 25;
    floatx4 acc[13][2];
#pragma unroll
    for (int nf = 0; nf < 13; ++nf) { acc[nf][0] = (floatx4)0.f; acc[nf][1] = (floatx4)0.f; }
    int r0 = row_base + col16, r1 = row_base + 16 + col16;

    for (int c = c0; c < c0 + 25; ++c) {
        int k0 = c * 32;
        for (int i = t; i < 208 * 4; i += 256) {
            int n = i >> 2, part = i & 3;
            *(halfx8*)&Bs[n * 40 + part * 8] =
                *(const halfx8*)&Wt[(size_t)n * FLATSZ + k0 + part * 8];
        }
        __syncthreads();
        int koff = k0 + quad * 8;
        halfx8 a0 = *(const halfx8*)&Ph[(size_t)r0 * FLATSZ + koff];
        halfx8 a1 = *(const halfx8*)&Ph[(size_t)r1 * FLATSZ + koff];
#pragma unroll
        for (int nf = 0; nf < 13; ++nf) {
            halfx8 b = *(const halfx8*)&Bs[(nf * 16 + col16) * 40 + quad * 8];
            acc[nf][0] = __builtin_amdgcn_mfma_f32_16x16x32_f16(a0, b, acc[nf][0], 0, 0, 0);
            acc[nf][1] = __builtin_amdgcn_mfma_f32_16x16x32_f16(a1, b, acc[nf][1], 0, 0, 0);
        }
        __syncthreads();
    }
#pragma unroll
    for (int nf = 0; nf < 13; ++nf) {
        int colg = nf * 16 + col16;
        if (colg >= 200) continue;
#pragma unroll
        for (int h = 0; h < 2; ++h) {
            int rbase = row_base + h * 16 + quad * 4;
#pragma unroll
            for (int j = 0; j < 4; ++j)
                gAtomicAdd(&C[(size_t)(rbase + j) * 200 + colg], acc[nf][h][j]);
        }
    }
}

// ---------------------------------------------------------------- stats / bn
__global__ __launch_bounds__(256) void colstats(
    const float* __restrict__ X, int M, int rpb,
    double* __restrict__ s1, double* __restrict__ s2)
{
    int c = threadIdx.x;
    if (c >= 200) return;
    int r0 = blockIdx.x * rpb;
    int r1 = min(r0 + rpb, M);
    float sum = 0.f, sq = 0.f;
    for (int rr = r0; rr < r1; ++rr) {
        float v = X[(size_t)rr * 200 + c];
        sum += v; sq += v * v;
    }
    gAtomicAdd(&s1[c], (double)sum);
    gAtomicAdd(&s2[c], (double)sq);
}

__global__ void finalize_stats(const double* __restrict__ s1, const double* __restrict__ s2,
                               const float* __restrict__ g, const float* __restrict__ bb,
                               float* __restrict__ sc, float* __restrict__ sh,
                               int ncols, double count)
{
    int c = threadIdx.x;
    if (c >= ncols) return;
    double m = s1[c] / count;
    double v = s2[c] / count - m * m;
    double scd = (double)g[c] / sqrt(v + 1e-5);
    sc[c] = (float)scd;
    sh[c] = (float)((double)bb[c] - m * scd);
}

__global__ __launch_bounds__(256) void bn_act_200(
    float* __restrict__ X, const float* __restrict__ sc, const float* __restrict__ sh,
    long n4, int act)
{
    long stride = (long)gridDim.x * blockDim.x;
    for (long i = (long)blockIdx.x * blockDim.x + threadIdx.x; i < n4; i += stride) {
        int c4 = (int)(i % 50) * 4;
        float4 v = ((const float4*)X)[i];
        float a0 = v.x * sc[c4 + 0] + sh[c4 + 0];
        float a1 = v.y * sc[c4 + 1] + sh[c4 + 1];
        float a2 = v.z * sc[c4 + 2] + sh[c4 + 2];
        float a3 = v.w * sc[c4 + 3] + sh[c4 + 3];
        if (act == 0) { a0 = tanhf(a0); a1 = tanhf(a1); a2 = tanhf(a2); a3 = tanhf(a3); }
        else { a0 = fmaxf(a0, 0.f); a1 = fmaxf(a1, 0.f); a2 = fmaxf(a2, 0.f); a3 = fmaxf(a3, 0.f); }
        ((float4*)X)[i] = make_float4(a0, a1, a2, a3);
    }
}

__global__ __launch_bounds__(256) void init_bias200(
    float* __restrict__ C, const float* __restrict__ b, long n)
{
    long stride = (long)gridDim.x * blockDim.x;
    for (long i = (long)blockIdx.x * blockDim.x + threadIdx.x; i < n; i += stride)
        C[i] = b[(int)(i % 200)];
}

__global__ __launch_bounds__(256) void rel_mm(
    const float* __restrict__ R, const float* __restrict__ W, float* __restrict__ O)
{
    int idx = blockIdx.x * blockDim.x + threadIdx.x;
    if (idx >= 200 * 200) return;
    int row = idx / 200, col = idx - row * 200;
    float acc = 0.f;
    for (int k = 0; k < 200; ++k) acc = fmaf(R[row * 200 + k], W[k * 200 + col], acc);
    O[idx] = acc;
}

__global__ __launch_bounds__(256) void build_stk(
    const float* __restrict__ x2, const float* __restrict__ r2,
    const int* __restrict__ subj, const int* __restrict__ ridx,
    float* __restrict__ stk, double* __restrict__ s1, double* __restrict__ s2)
{
    int b = blockIdx.x, t = threadIdx.x;
    const float* se = x2 + (size_t)subj[b] * DIM;
    const float* re = r2 + (size_t)ridx[b] * DIM;
    float sum = 0.f, sq = 0.f;
    for (int i = t; i < 400; i += 256) {
        float v = (i < 200) ? se[i] : re[i - 200];
        stk[(size_t)b * 400 + i] = v;
        sum += v; sq += v * v;
    }
    for (int off = 32; off > 0; off >>= 1) {
        sum += __shfl_down(sum, off);
        sq  += __shfl_down(sq, off);
    }
    if ((t & 63) == 0) { gAtomicAdd(&s1[0], (double)sum); gAtomicAdd(&s2[0], (double)sq); }
}

__global__ __launch_bounds__(256) void conv_fwd(
    const float* __restrict__ stk, const float* __restrict__ conv_w,
    const float* __restrict__ conv_b, const float* __restrict__ sc0,
    const float* __restrict__ sh0, _Float16* __restrict__ Ph,
    double* __restrict__ s1, double* __restrict__ s2)
{
    __shared__ float img[400];
    __shared__ float wsm[9800];
    __shared__ float bsm[200];
    __shared__ float fsum[200];
    __shared__ float fsq[200];
    int b = blockIdx.x, t = threadIdx.x;
    float scale0 = sc0[0], shift0 = sh0[0];
    if (t < 200) { fsum[t] = 0.f; fsq[t] = 0.f; bsm[t] = conv_b[t]; }
    for (int i = t; i < 400; i += 256) img[i] = stk[(size_t)b * 400 + i] * scale0 + shift0;
    for (int i = t; i < 9800; i += 256) wsm[i] = conv_w[i];
    __syncthreads();
    for (int fy = t; fy < 2800; fy += 256) {
        int f = fy / 14, y = fy - (fy / 14) * 14;
        const float* wf = &wsm[f * 49];
        float acc[14];
        float bias = bsm[f];
#pragma unroll
        for (int xx = 0; xx < 14; ++xx) acc[xx] = bias;
#pragma unroll
        for (int i = 0; i < 7; ++i) {
            const float* rowp = &img[(y + i) * 20];
            float rv[20];
#pragma unroll
            for (int c = 0; c < 20; ++c) rv[c] = rowp[c];
#pragma unroll
            for (int j = 0; j < 7; ++j) {
                float wv = wf[i * 7 + j];
#pragma unroll
                for (int xx = 0; xx < 14; ++xx) acc[xx] = fmaf(rv[xx + j], wv, acc[xx]);
            }
        }
        float ls = 0.f, lq = 0.f;
        _Float16* pp = Ph + (size_t)b * FLATSZ + (size_t)f * 196 + y * 14;
#pragma unroll
        for (int xx = 0; xx < 14; ++xx) {
            float v = acc[xx];
            pp[xx] = (_Float16)v;
            ls += v; lq += v * v;
        }
        atomicAdd(&fsum[f], ls);
        atomicAdd(&fsq[f], lq);
    }
    __syncthreads();
    if (t < 200) {
        gAtomicAdd(&s1[t], (double)fsum[t]);
        gAtomicAdd(&s2[t], (double)fsq[t]);
    }
}

__global__ __launch_bounds__(256) void bn1_relu_f16(
    _Float16* __restrict__ Ph, const float* __restrict__ sc, const float* __restrict__ sh)
{
    long n4 = (long)NB * (FLATSZ / 4);
    long stride = (long)gridDim.x * blockDim.x;
    for (long i = (long)blockIdx.x * blockDim.x + threadIdx.x; i < n4; i += stride) {
        int k4 = (int)(i % (FLATSZ / 4));
        int f = k4 / 49;
        float s = sc[f], h = sh[f];
        halfx4 v = ((const halfx4*)Ph)[i];
#pragma unroll
        for (int e = 0; e < 4; ++e) {
            float x = (float)v[e];
            x = fmaxf(x * s + h, 0.f);
            v[e] = (_Float16)x;
        }
        ((halfx4*)Ph)[i] = v;
    }
}

__global__ __launch_bounds__(256) void score_mm(
    const float* __restrict__ Hn, const float* __restrict__ x2,
    const int* __restrict__ obj, float* __restrict__ out)
{
    __shared__ float Asm[16][17];
    __shared__ float Bsm[16][17];
    int tx = threadIdx.x & 15, ty = threadIdx.x >> 4;
    int row = blockIdx.y * 16 + ty;
    int col = blockIdx.x * 16 + tx;
    int oj = obj[blockIdx.x * 16 + ty];
    float acc = 0.f;
    for (int k0 = 0; k0 < 200; k0 += 16) {
        int k = k0 + tx;
        Asm[ty][tx] = (k < 200) ? Hn[(size_t)row * 200 + k] : 0.f;
        Bsm[ty][tx] = (k < 200) ? x2[(size_t)oj * 200 + k] : 0.f;
        __syncthreads();
#pragma unroll
        for (int kk = 0; kk < 16; ++kk) acc = fmaf(Asm[ty][kk], Bsm[tx][kk], acc);
        __syncthreads();
    }
    out[(size_t)row * NB + col] = 1.f / (1.f + expf(-acc));
}

// ---------------------------------------------------------------- driver
extern "C" void kernel_launch(void* const* d_in, const int* in_sizes, int n_in,
                              void* d_out, int out_size, void* d_ws, size_t ws_size,
                              hipStream_t stream)
{
    (void)in_sizes; (void)n_in; (void)out_size;
    const float* init_embed = (const float*)d_in[0];
    const float* init_rel   = (const float*)d_in[1];
    const float* edge_norm  = (const float*)d_in[2];
    const float* w_in1  = (const float*)d_in[3];
    const float* w_out1 = (const float*)d_in[4];
    const float* w_loop1= (const float*)d_in[5];
    const float* w_rel1 = (const float*)d_in[6];
    const float* lrel1  = (const float*)d_in[7];
    const float* b1     = (const float*)d_in[8];
    const float* gm1    = (const float*)d_in[9];
    const float* be1    = (const float*)d_in[10];
    const float* w_in2  = (const float*)d_in[11];
    const float* w_out2 = (const float*)d_in[12];
    const float* w_loop2= (const float*)d_in[13];
    const float* w_rel2 = (const float*)d_in[14];
    const float* lrel2  = (const float*)d_in[15];
    const float* b2     = (const float*)d_in[16];
    const float* gm2    = (const float*)d_in[17];
    const float* be2    = (const float*)d_in[18];
    const float* conv_w = (const float*)d_in[19];
    const float* conv_b = (const float*)d_in[20];
    const float* fc_w   = (const float*)d_in[21];
    const float* fc_b   = (const float*)d_in[22];
    const float* bn0_g  = (const float*)d_in[23];
    const float* bn0_b  = (const float*)d_in[24];
    const float* bn1_g  = (const float*)d_in[25];
    const float* bn1_b  = (const float*)d_in[26];
    const float* bn2_g  = (const float*)d_in[27];
    const float* bn2_b  = (const float*)d_in[28];
    const int* subj   = (const int*)d_in[29];
    const int* relidx = (const int*)d_in[30];
    const int* obj    = (const int*)d_in[31];
    const int* src    = (const int*)d_in[32];
    const int* dst    = (const int*)d_in[33];
    const int* etype  = (const int*)d_in[34];

    float* ws = (float*)d_ws;
    float* R0 = ws;                        // x1, later Ph (fp16 conv out)
    float* R1 = ws + REGF;                 // aggI, layer2 C in-place -> x2
    float* R2 = ws + 2 * REGF;             // aggO, later fch (fp16 fc weights)
    float* p = ws + 3 * REGF;              // tail
    float* r1v = p;            p += 40000;
    float* r2v = p;            p += 40000;
    float* stk = p;            p += 409600;
    float* hfc = p;            p += 204800;
    float* fsc = p;            p += 256;
    float* fsh = p;            p += 256;
    double* ds1 = (double*)p;  p += 512;   // 256 doubles
    double* ds2 = (double*)p;  p += 512;   // 256 doubles (contiguous after ds1)
    short* Wp = (short*)p;     p += (6 * WPLANE) / 2;
    int* hist = (int*)p;       p += NENT;
    int* offs = (int*)p;       p += NENT + 1;
    int* cursor = (int*)p;     p += NENT;
    int* bsum = (int*)p;       p += 512;
    int* es = (int*)p;         p += NEDGE;
    int* et = (int*)p;         p += NEDGE;
    float* en = p;             p += NEDGE;

    float* x1 = R0;
    float* aggI = R1;
    float* aggO = R2;
    _Float16* Ph  = (_Float16*)R0;
    _Float16* fch = (_Float16*)R2;

    const size_t NEED = (size_t)(p - ws) * sizeof(float);
    if (ws_size < NEED) return;

    const int NBLK = (NENT + 255) / 256;   // 391
    const size_t DSBYTES = 512 * sizeof(double);   // ds1(256) + ds2(256) doubles

    // -------- CSR build --------
    hipMemsetAsync(hist, 0, NENT * sizeof(int), stream);
    edge_hist<<<1024, 256, 0, stream>>>(dst, hist);
    scan1<<<NBLK, 256, 0, stream>>>(hist, offs, bsum);
    scan2<<<1, 64, 0, stream>>>(bsum, NBLK);
    scan3<<<NBLK, 256, 0, stream>>>(hist, offs, bsum, cursor);
    edge_fill<<<1024, 256, 0, stream>>>(src, dst, etype, edge_norm, cursor, es, et, en);

    // -------- one CompGCN layer --------
    auto run_layer = [&](const float* xin, const float* rin,
                         const float* wi, const float* wo, const float* wl,
                         const float* wr, const float* lrel, const float* bias,
                         const float* gg, const float* bbeta,
                         float* hout, float* rout) {
        pack_w3<<<(3 * WPLANE + 255) / 256, 256, 0, stream>>>(wi, wo, wl, Wp);
        gather_nodes<<<(NENT + 3) / 4, 256, 0, stream>>>(xin, rin, offs, es, et, en,
                                                         aggI, aggO);
        hipMemsetAsync(ds1, 0, DSBYTES, stream);
        gemm_mfma<<<(NENT + 127) / 128, 256, 0, stream>>>(
            aggI, aggO, xin, lrel, Wp, Wp + 3 * WPLANE, hout, bias, 1.f / 3.f, NENT,
            ds1, ds2);
        finalize_stats<<<1, 256, 0, stream>>>(ds1, ds2, gg, bbeta, fsc, fsh, 200, (double)NENT);
        bn_act_200<<<4096, 256, 0, stream>>>(hout, fsc, fsh, (long)NENT * 50, 0);
        rel_mm<<<(40000 + 255) / 256, 256, 0, stream>>>(rin, wr, rout);
    };

    run_layer(init_embed, init_rel, w_in1, w_out1, w_loop1, w_rel1, lrel1, b1, gm1, be1,
              x1, r1v);
    run_layer(x1, r1v, w_in2, w_out2, w_loop2, w_rel2, lrel2, b2, gm2, be2,
              aggI, r2v);
    float* x2 = aggI;

    // -------- ConvE head --------
    hipMemsetAsync(ds1, 0, DSBYTES, stream);
    build_stk<<<NB, 256, 0, stream>>>(x2, r2v, subj, relidx, stk, ds1, ds2);
    finalize_stats<<<1, 256, 0, stream>>>(ds1, ds2, bn0_g, bn0_b, fsc, fsh, 1,
                                          (double)((long)NB * 400));
    hipMemsetAsync(ds1, 0, DSBYTES, stream);
    conv_fwd<<<NB, 256, 0, stream>>>(stk, conv_w, conv_b, fsc, fsh, Ph, ds1, ds2);
    finalize_stats<<<1, 256, 0, stream>>>(ds1, ds2, bn1_g, bn1_b, fsc, fsh, 200,
                                          (double)((long)NB * 196));
    bn1_relu_f16<<<4096, 256, 0, stream>>>(Ph, fsc, fsh);
    pack_fcw<<<(int)(((long)208 * FLATSZ + 255) / 256), 256, 0, stream>>>(fc_w, fch);
    init_bias200<<<800, 256, 0, stream>>>(hfc, fc_b, (long)NB * 200);
    fc_gemm<<<dim3(8, 49), 256, 0, stream>>>(Ph, fch, hfc);
    hipMemsetAsync(ds1, 0, DSBYTES, stream);
    colstats<<<4, 256, 0, stream>>>(hfc, NB, 256, ds1, ds2);
    finalize_stats<<<1, 256, 0, stream>>>(ds1, ds2, bn2_g, bn2_b, fsc, fsh, 200, (double)NB);
    bn_act_200<<<200, 256, 0, stream>>>(hfc, fsc, fsh, (long)NB * 50, 1);
    score_mm<<<dim3(NB / 16, NB / 16), 256, 0, stream>>>(hfc, x2, obj, (float*)d_out);
}